// Round 16
// baseline (1901.265 us; speedup 1.0000x reference)
//
#include <hip/hip_runtime.h>
#include <math.h>
#include <limits.h>

#define FDIM 512
#define HIDN 256
#define NBAGS 8
#define NINST 16384
#define NNODE 8200
#define NEDGE 32800
#define BFSPLIT 16
#define SPLITW 513
#define MCHUNK 128

typedef __attribute__((ext_vector_type(8))) short short8v;   // 8 bf16 (4 VGPR)
typedef __attribute__((ext_vector_type(4))) float f32x4v;    // MFMA C/D frag

__device__ __forceinline__ float lrelu(float v, float s){ return v >= 0.f ? v : v*s; }

// sorted-4 insert with jax.lax.top_k tie semantics (lower index wins ties)
__device__ __forceinline__ void ins4(float v, int id, float* tv, int* ti){
    if ((v > tv[3]) || (v == tv[3] && id < ti[3])){
        tv[3]=v; ti[3]=id;
#pragma unroll
        for (int q=3;q>0;--q){
            bool sw = (tv[q] > tv[q-1]) || (tv[q]==tv[q-1] && ti[q]<ti[q-1]);
            if (sw){ float f=tv[q]; tv[q]=tv[q-1]; tv[q-1]=f; int d=ti[q]; ti[q]=ti[q-1]; ti[q-1]=d; }
        }
    }
}

__device__ __forceinline__ void ins8(float v, int id, float* tv, int* ti){
    if ((v > tv[7]) || (v == tv[7] && id < ti[7])){
        tv[7]=v; ti[7]=id;
#pragma unroll
        for (int q=7;q>0;--q){
            bool sw = (tv[q] > tv[q-1]) || (tv[q]==tv[q-1] && ti[q]<ti[q-1]);
            if (sw){ float f=tv[q]; tv[q]=tv[q-1]; tv[q-1]=f; int d=ti[q]; ti[q]=ti[q-1]; ti[q-1]=d; }
        }
    }
}

__device__ __forceinline__ unsigned short f2bf(float f){
    unsigned u = __float_as_uint(f);
    unsigned r = u + 0x7FFFu + ((u >> 16) & 1u);   // round-to-nearest-even
    return (unsigned short)(r >> 16);
}
__device__ __forceinline__ float bf2f(unsigned short h){
    return __uint_as_float((unsigned)h << 16);
}

// ---------------------------------------------------------------------------
// 512x512 weight split: WThi/WTlo[n][k] = bf16 hi/lo of W[k][n] (transposed)
// ---------------------------------------------------------------------------
__global__ void k_wsplit(const float* __restrict__ W,
        unsigned short* __restrict__ WThi, unsigned short* __restrict__ WTlo){
    int i = blockIdx.x*256 + threadIdx.x;          // i over 512*512
    int k = i >> 9, n = i & 511;
    float w = W[i];                                 // W[k][n]
    unsigned short hi = f2bf(w);
    unsigned short lo = f2bf(w - bf2f(hi));
    WThi[(size_t)n*512 + k] = hi;
    WTlo[(size_t)n*512 + k] = lo;
}

// ---------------------------------------------------------------------------
// scores via bf16x3 split MFMA (round-15 validated: LDS + register prefetch)
// ---------------------------------------------------------------------------
__global__ __launch_bounds__(256) void k_scores(const float* __restrict__ X,
        const unsigned short* __restrict__ WThi, const unsigned short* __restrict__ WTlo,
        const float* __restrict__ b1, const float* __restrict__ v2,
        float* __restrict__ scoresP)
{
    __shared__ unsigned short Ahi[128][40];
    __shared__ unsigned short Alo[128][40];
    __shared__ unsigned short Bhi[128][40];
    __shared__ unsigned short Blo[128][40];
    int t = threadIdx.x;
    int wv = t >> 6, lane = t & 63;
    int lcol = lane & 15, lk = lane >> 4;
    size_t mb = (size_t)blockIdx.y * 128;
    int nb = blockIdx.x * 128;

    f32x4v acc[2][8];
#pragma unroll
    for (int rf=0;rf<2;rf++)
#pragma unroll
        for (int cf=0;cf<8;cf++) acc[rf][cf] = (f32x4v){0.f,0.f,0.f,0.f};

    int segA = t & 7, rowA = t >> 3;
    int colB = t >> 2, partB = t & 3;

    float4 pa[4];
    short8v pwh[2], pwl[2];
#pragma unroll
    for (int q=0;q<4;q++)
        pa[q] = *(const float4*)(X + (mb + rowA + q*32)*512 + segA*4);
#pragma unroll
    for (int q=0;q<2;q++){
        int col = colB + q*64;
        pwh[q] = *(const short8v*)(WThi + (size_t)(nb+col)*512 + partB*8);
        pwl[q] = *(const short8v*)(WTlo + (size_t)(nb+col)*512 + partB*8);
    }

    for (int kc = 0; kc < 512; kc += 32){
        __syncthreads();
#pragma unroll
        for (int q=0;q<4;q++){
            float4 v = pa[q];
            ushort4 h, l;
            h.x=f2bf(v.x); h.y=f2bf(v.y); h.z=f2bf(v.z); h.w=f2bf(v.w);
            l.x=f2bf(v.x-bf2f(h.x)); l.y=f2bf(v.y-bf2f(h.y));
            l.z=f2bf(v.z-bf2f(h.z)); l.w=f2bf(v.w-bf2f(h.w));
            *(ushort4*)&Ahi[rowA + q*32][segA*4] = h;
            *(ushort4*)&Alo[rowA + q*32][segA*4] = l;
        }
#pragma unroll
        for (int q=0;q<2;q++){
            *(short8v*)&Bhi[colB + q*64][partB*8] = pwh[q];
            *(short8v*)&Blo[colB + q*64][partB*8] = pwl[q];
        }
        __syncthreads();
        if (kc + 32 < 512){
            int kn = kc + 32;
#pragma unroll
            for (int q=0;q<4;q++)
                pa[q] = *(const float4*)(X + (mb + rowA + q*32)*512 + kn + segA*4);
#pragma unroll
            for (int q=0;q<2;q++){
                int col = colB + q*64;
                pwh[q] = *(const short8v*)(WThi + (size_t)(nb+col)*512 + kn + partB*8);
                pwl[q] = *(const short8v*)(WTlo + (size_t)(nb+col)*512 + kn + partB*8);
            }
        }
        int r0 = wv*32;
        short8v ah0 = *(const short8v*)&Ahi[r0      + lcol][lk*8];
        short8v al0 = *(const short8v*)&Alo[r0      + lcol][lk*8];
        short8v ah1 = *(const short8v*)&Ahi[r0 + 16 + lcol][lk*8];
        short8v al1 = *(const short8v*)&Alo[r0 + 16 + lcol][lk*8];
#pragma unroll
        for (int cf=0; cf<8; cf++){
            short8v bh = *(const short8v*)&Bhi[cf*16 + lcol][lk*8];
            short8v bl = *(const short8v*)&Blo[cf*16 + lcol][lk*8];
            acc[0][cf] = __builtin_amdgcn_mfma_f32_16x16x32_bf16(ah0, bh, acc[0][cf], 0,0,0);
            acc[0][cf] = __builtin_amdgcn_mfma_f32_16x16x32_bf16(ah0, bl, acc[0][cf], 0,0,0);
            acc[0][cf] = __builtin_amdgcn_mfma_f32_16x16x32_bf16(al0, bh, acc[0][cf], 0,0,0);
            acc[1][cf] = __builtin_amdgcn_mfma_f32_16x16x32_bf16(ah1, bh, acc[1][cf], 0,0,0);
            acc[1][cf] = __builtin_amdgcn_mfma_f32_16x16x32_bf16(ah1, bl, acc[1][cf], 0,0,0);
            acc[1][cf] = __builtin_amdgcn_mfma_f32_16x16x32_bf16(al1, bh, acc[1][cf], 0,0,0);
        }
    }
    float rowsum[2][4];
#pragma unroll
    for (int rf=0;rf<2;rf++)
#pragma unroll
        for (int r=0;r<4;r++) rowsum[rf][r]=0.f;
#pragma unroll
    for (int rf=0; rf<2; rf++)
#pragma unroll
        for (int cf=0; cf<8; cf++){
            int gc = nb + cf*16 + lcol;
            float bb = b1[gc], vv = v2[gc];
#pragma unroll
            for (int r=0;r<4;r++){
                float h = acc[rf][cf][r] + bb;
                h = h > 0.f ? h : 0.f;
                rowsum[rf][r] = fmaf(h, vv, rowsum[rf][r]);
            }
        }
#pragma unroll
    for (int mask=1; mask<16; mask<<=1)
#pragma unroll
        for (int rf=0;rf<2;rf++)
#pragma unroll
            for (int r=0;r<4;r++)
                rowsum[rf][r] += __shfl_xor(rowsum[rf][r], mask);
    if (lcol == 0){
#pragma unroll
        for (int rf=0;rf<2;rf++)
#pragma unroll
            for (int r=0;r<4;r++){
                size_t grow = mb + wv*32 + rf*16 + lk*4 + r;
                scoresP[(size_t)blockIdx.x*(NBAGS*NINST) + grow] = rowsum[rf][r];
            }
    }
}

// ---------------------------------------------------------------------------
// generic bf16x3 MFMA GEMM (round-15 validated: LDS + register prefetch)
// ---------------------------------------------------------------------------
__global__ __launch_bounds__(256) void k_gemm3(const float* __restrict__ X,
        const unsigned short* __restrict__ WThi, const unsigned short* __restrict__ WTlo,
        const float* __restrict__ bias, float* __restrict__ C,
        int M, int N, int K, float slope)
{
    __shared__ unsigned short Ahi[128][40];
    __shared__ unsigned short Alo[128][40];
    __shared__ unsigned short Bhi[128][40];
    __shared__ unsigned short Blo[128][40];
    int t = threadIdx.x;
    int wv = t >> 6, lane = t & 63;
    int lcol = lane & 15, lk = lane >> 4;
    int mb = blockIdx.y * 128;
    int nb = blockIdx.x * 128;

    f32x4v acc[2][8];
#pragma unroll
    for (int rf=0;rf<2;rf++)
#pragma unroll
        for (int cf=0;cf<8;cf++) acc[rf][cf] = (f32x4v){0.f,0.f,0.f,0.f};

    int segA = t & 7, rowA = t >> 3;
    int colB = t >> 2, partB = t & 3;
    int grA[4];
#pragma unroll
    for (int q=0;q<4;q++){
        int gr = mb + rowA + q*32; if (gr >= M) gr = M-1;
        grA[q] = gr;
    }

    float4 pa[4];
    short8v pwh[2], pwl[2];
#pragma unroll
    for (int q=0;q<4;q++)
        pa[q] = *(const float4*)(X + (size_t)grA[q]*K + segA*4);
#pragma unroll
    for (int q=0;q<2;q++){
        int col = colB + q*64;
        pwh[q] = *(const short8v*)(WThi + (size_t)(nb+col)*K + partB*8);
        pwl[q] = *(const short8v*)(WTlo + (size_t)(nb+col)*K + partB*8);
    }

    for (int kc = 0; kc < K; kc += 32){
        __syncthreads();
#pragma unroll
        for (int q=0;q<4;q++){
            float4 v = pa[q];
            ushort4 h, l;
            h.x=f2bf(v.x); h.y=f2bf(v.y); h.z=f2bf(v.z); h.w=f2bf(v.w);
            l.x=f2bf(v.x-bf2f(h.x)); l.y=f2bf(v.y-bf2f(h.y));
            l.z=f2bf(v.z-bf2f(h.z)); l.w=f2bf(v.w-bf2f(h.w));
            *(ushort4*)&Ahi[rowA + q*32][segA*4] = h;
            *(ushort4*)&Alo[rowA + q*32][segA*4] = l;
        }
#pragma unroll
        for (int q=0;q<2;q++){
            *(short8v*)&Bhi[colB + q*64][partB*8] = pwh[q];
            *(short8v*)&Blo[colB + q*64][partB*8] = pwl[q];
        }
        __syncthreads();
        if (kc + 32 < K){
            int kn = kc + 32;
#pragma unroll
            for (int q=0;q<4;q++)
                pa[q] = *(const float4*)(X + (size_t)grA[q]*K + kn + segA*4);
#pragma unroll
            for (int q=0;q<2;q++){
                int col = colB + q*64;
                pwh[q] = *(const short8v*)(WThi + (size_t)(nb+col)*K + kn + partB*8);
                pwl[q] = *(const short8v*)(WTlo + (size_t)(nb+col)*K + kn + partB*8);
            }
        }
        int r0 = wv*32;
        short8v ah0 = *(const short8v*)&Ahi[r0      + lcol][lk*8];
        short8v al0 = *(const short8v*)&Alo[r0      + lcol][lk*8];
        short8v ah1 = *(const short8v*)&Ahi[r0 + 16 + lcol][lk*8];
        short8v al1 = *(const short8v*)&Alo[r0 + 16 + lcol][lk*8];
#pragma unroll
        for (int cf=0; cf<8; cf++){
            short8v bh = *(const short8v*)&Bhi[cf*16 + lcol][lk*8];
            short8v bl = *(const short8v*)&Blo[cf*16 + lcol][lk*8];
            acc[0][cf] = __builtin_amdgcn_mfma_f32_16x16x32_bf16(ah0, bh, acc[0][cf], 0,0,0);
            acc[0][cf] = __builtin_amdgcn_mfma_f32_16x16x32_bf16(ah0, bl, acc[0][cf], 0,0,0);
            acc[0][cf] = __builtin_amdgcn_mfma_f32_16x16x32_bf16(al0, bh, acc[0][cf], 0,0,0);
            acc[1][cf] = __builtin_amdgcn_mfma_f32_16x16x32_bf16(ah1, bh, acc[1][cf], 0,0,0);
            acc[1][cf] = __builtin_amdgcn_mfma_f32_16x16x32_bf16(ah1, bl, acc[1][cf], 0,0,0);
            acc[1][cf] = __builtin_amdgcn_mfma_f32_16x16x32_bf16(al1, bh, acc[1][cf], 0,0,0);
        }
    }
#pragma unroll
    for (int rf=0; rf<2; rf++)
#pragma unroll
        for (int cf=0; cf<8; cf++){
            int gc = nb + cf*16 + lcol;
            float bb = bias ? bias[gc] : 0.f;
#pragma unroll
            for (int r=0;r<4;r++){
                int grow = mb + wv*32 + rf*16 + lk*4 + r;
                if (grow < M){
                    float v = acc[rf][cf][r] + bb;
                    C[(size_t)grow*N + gc] = lrelu(v, slope);
                }
            }
        }
}

__global__ void k_scred(const float* __restrict__ sp, float* __restrict__ s){
    int r = blockIdx.x*256+threadIdx.x;
    if (r < NBAGS*NINST)
        s[r] = sp[r] + sp[NBAGS*NINST + r] + sp[2*NBAGS*NINST + r] + sp[3*NBAGS*NINST + r];
}

// softmax over 16384 per bag, in place
__global__ __launch_bounds__(256) void k_softmax(float* __restrict__ s0){
    int b = blockIdx.x; float* s = s0 + (size_t)b*NINST;
    __shared__ float red[256];
    int t = threadIdx.x;
    float m = -INFINITY;
    for (int i=t;i<NINST;i+=256) m = fmaxf(m, s[i]);
    red[t]=m; __syncthreads();
    for (int st=128; st>0; st>>=1){ if(t<st) red[t]=fmaxf(red[t],red[t+st]); __syncthreads(); }
    m = red[0]; __syncthreads();
    float sum=0.f;
    for (int i=t;i<NINST;i+=256) sum += __expf(s[i]-m);
    red[t]=sum; __syncthreads();
    for (int st=128; st>0; st>>=1){ if(t<st) red[t]+=red[t+st]; __syncthreads(); }
    float inv = 1.f/red[0];
    for (int i=t;i<NINST;i+=256) s[i] = __expf(s[i]-m)*inv;
}

// M partials: MP[(chunk*8+b)*512+d]; 128 chunks x 8 bags = 1024 blocks
__global__ __launch_bounds__(256) void k_M(const float* __restrict__ x,
        const float* __restrict__ A, float* __restrict__ MP){
    int b = blockIdx.y; int chunk = blockIdx.x;
    int n0 = chunk*(NINST/MCHUNK);
    __shared__ float As[NINST/MCHUNK];
    int t=threadIdx.x;
    if (t < NINST/MCHUNK) As[t] = A[(size_t)b*NINST+n0+t];
    __syncthreads();
    float a0=0.f, a1=0.f;
    const float* xb = x + ((size_t)b*NINST + n0)*FDIM;
    for (int n=0;n<NINST/MCHUNK;n++){
        float w = As[n];
        a0 = fmaf(w, xb[(size_t)n*FDIM + t],       a0);
        a1 = fmaf(w, xb[(size_t)n*FDIM + t + 256], a1);
    }
    MP[((size_t)chunk*NBAGS + b)*FDIM + t]       = a0;
    MP[((size_t)chunk*NBAGS + b)*FDIM + t + 256] = a1;
}

__global__ void k_Mred(const float* __restrict__ mp, float* __restrict__ M_){
    int b = blockIdx.x; int d = threadIdx.x; // 512 threads
    float s=0.f;
    for (int c=0;c<MCHUNK;c++) s += mp[((size_t)c*NBAGS+b)*FDIM + d];
    M_[b*FDIM+d]=s;
}

__global__ void k_logits_mlp(const float* __restrict__ M_, const float* __restrict__ cW,
        const float* __restrict__ cb, float* __restrict__ outp){
    int t = threadIdx.x;
    if (t < 16){
        int r=t>>1, c=t&1;
        float s=cb[c];
        for (int k=0;k<FDIM;k++) s = fmaf(M_[r*FDIM+k], cW[k*2+c], s);
        outp[r*2+c] = s;
    }
}

__global__ void k_xc(const float* __restrict__ M_, const float* __restrict__ reh, float* __restrict__ xc){
    size_t i = (size_t)blockIdx.x*256 + threadIdx.x;
    if (i >= (size_t)NNODE*FDIM) return;
    xc[i] = (i < (size_t)NBAGS*FDIM) ? M_[i] : reh[i - (size_t)NBAGS*FDIM];
}

// ---------------------------------------------------------------------------
// fp32 GEMM (projector only — keeps xg bit-exact for the exact kNN rescore)
// ---------------------------------------------------------------------------
__global__ __launch_bounds__(256) void k_gemm(const float* __restrict__ X,
        const float* __restrict__ W, const float* __restrict__ bias,
        float* __restrict__ C, unsigned short* __restrict__ Cbf,
        int M, int N, int K, float slope)
{
    __shared__ float As[32][68];
    __shared__ float Ws[32][128];
    int t = threadIdx.x; int tx = t & 15, ty = t >> 4;
    int mb = blockIdx.y * 64, nb = blockIdx.x * 128;
    float acc[4][8];
#pragma unroll
    for (int i=0;i<4;i++)
#pragma unroll
        for (int j=0;j<8;j++) acc[i][j]=0.f;

    int kq=(t&7)*4, m0=t>>3;
    int n4=(t&31)*4, k0=t>>5;
    for (int kc=0;kc<K;kc+=32){
#pragma unroll
        for (int mm=0;mm<2;mm++){
            int m = m0 + mm*32;
            int gr = mb + m; if (gr >= M) gr = M-1;
            float4 v = *(const float4*)(X + (size_t)gr*K + kc + kq);
            As[kq+0][m]=v.x; As[kq+1][m]=v.y; As[kq+2][m]=v.z; As[kq+3][m]=v.w;
        }
#pragma unroll
        for (int kk=0;kk<4;kk++){
            float4 v = *(const float4*)(W + (size_t)(kc+k0+kk*8)*N + nb + n4);
            *(float4*)&Ws[k0+kk*8][n4] = v;
        }
        __syncthreads();
#pragma unroll 4
        for (int k=0;k<32;k++){
            float4 a = *(const float4*)&As[k][ty*4];
            float4 b0 = *(const float4*)&Ws[k][tx*4];
            float4 b1 = *(const float4*)&Ws[k][64+tx*4];
            float av[4]={a.x,a.y,a.z,a.w};
            float bv[8]={b0.x,b0.y,b0.z,b0.w,b1.x,b1.y,b1.z,b1.w};
#pragma unroll
            for (int i=0;i<4;i++)
#pragma unroll
                for (int j=0;j<8;j++)
                    acc[i][j] = fmaf(av[i], bv[j], acc[i][j]);
        }
        __syncthreads();
    }
#pragma unroll
    for (int i=0;i<4;i++){
        int gr = mb + ty*4 + i;
        if (gr >= M) continue;
        float o[8];
#pragma unroll
        for (int j=0;j<8;j++){
            int gc = (j<4) ? (nb + tx*4 + j) : (nb + 64 + tx*4 + (j-4));
            float v = acc[i][j] + (bias ? bias[gc] : 0.f);
            o[j] = lrelu(v, slope);
        }
        float4 o0 = make_float4(o[0],o[1],o[2],o[3]);
        float4 o1 = make_float4(o[4],o[5],o[6],o[7]);
        *(float4*)(C + (size_t)gr*N + nb + tx*4)      = o0;
        *(float4*)(C + (size_t)gr*N + nb + 64 + tx*4) = o1;
        if (Cbf){
            ushort4 h0, h1;
            h0.x=f2bf(o[0]); h0.y=f2bf(o[1]); h0.z=f2bf(o[2]); h0.w=f2bf(o[3]);
            h1.x=f2bf(o[4]); h1.y=f2bf(o[5]); h1.z=f2bf(o[6]); h1.w=f2bf(o[7]);
            *(ushort4*)(Cbf + (size_t)gr*N + nb + tx*4)      = h0;
            *(ushort4*)(Cbf + (size_t)gr*N + nb + 64 + tx*4) = h1;
        }
    }
}

// row dot: mode 0: out[r] = X[r]·v ; mode 1: out[r] = 1/(sqrt(X[r]·X[r])+1e-12)
__global__ void k_rowdot(const float* __restrict__ X, const float* __restrict__ v,
        float* __restrict__ out, int K, int mode){
    int r = blockIdx.x; int t = threadIdx.x;
    const float* xr = X + (size_t)r*K;
    float s = 0.f;
    if (mode==1){ for (int k=t;k<K;k+=64){ float x_=xr[k]; s=fmaf(x_,x_,s);} }
    else        { for (int k=t;k<K;k+=64) s=fmaf(xr[k],v[k],s); }
    for (int off=32;off;off>>=1) s += __shfl_down(s, off);
    if (t==0) out[r] = (mode==1)? 1.f/(sqrtf(s)+1e-12f) : s;
}

// w2[k] = sum_j W[k][j]*att2[j]
__global__ void k_watt(const float* __restrict__ W, const float* __restrict__ att2, float* __restrict__ w2){
    int k = blockIdx.x; int t=threadIdx.x;
    float s=0.f;
    for (int j=t;j<FDIM;j+=64) s=fmaf(W[(size_t)k*FDIM+j], att2[j], s);
    for (int off=32;off;off>>=1) s += __shfl_down(s, off);
    if (t==0) w2[k]=s;
}

// ---------------------------------------------------------------------------
// bf16 MFMA prefilter v4: 32 rows per wave (two register-resident A-sets) —
// each B-fragment ds_read feeds FOUR MFMAs (2 rowsets x 2 split-K chains).
// Split-K pairing (a·0 + a·1) identical to the validated dual-chain version
// -> bit-identical prefilter values. LDS traffic per output row halves.
// Register prefetch of next tile (round-14 validated). Blocks of 128 rows.
// ---------------------------------------------------------------------------
__global__ __launch_bounds__(256) void k_simbf(const unsigned short* __restrict__ xgh,
        const float* __restrict__ rn, float* __restrict__ candV, int* __restrict__ candI)
{
    __shared__ unsigned short Bs[16][520];
    int t = threadIdx.x;
    int wv = t >> 6, lane = t & 63;
    int lcol = lane & 15, lk = lane >> 4;
    int split = blockIdx.x;
    int r0 = blockIdx.y * 128 + wv * 32;    // wave owns 32 rows

    short8v aF0[16], aF1[16];
    {
        int ar0 = r0 + lcol;      if (ar0 >= NNODE) ar0 = NNODE - 1;
        int ar1 = r0 + 16 + lcol; if (ar1 >= NNODE) ar1 = NNODE - 1;
        const unsigned short* ap0 = xgh + (size_t)ar0 * FDIM + lk * 8;
        const unsigned short* ap1 = xgh + (size_t)ar1 * FDIM + lk * 8;
#pragma unroll
        for (int s = 0; s < 16; s++){
            aF0[s] = *(const short8v*)(ap0 + s * 32);
            aF1[s] = *(const short8v*)(ap1 + s * 32);
        }
    }

    int c0 = split * SPLITW;
    int cend = c0 + SPLITW; if (cend > NNODE) cend = NNODE;

    float tv[8][4]; int ti[8][4];
#pragma unroll
    for (int i=0;i<8;i++)
#pragma unroll
        for (int q=0;q<4;q++){ tv[i][q]=-INFINITY; ti[i][q]=INT_MAX; }

    int rho = t >> 4, seg = t & 15;

    short8v pb[4];
    {
        int gc = c0 + rho; if (gc >= cend) gc = cend - 1;
        const unsigned short* bp = xgh + (size_t)gc * FDIM;
#pragma unroll
        for (int p = 0; p < 4; p++)
            pb[p] = *(const short8v*)(bp + seg*8 + p*128);
    }

    for (int cc = c0; cc < cend; cc += 16){
        __syncthreads();
#pragma unroll
        for (int p = 0; p < 4; p++)
            *(short8v*)&Bs[rho][seg*8 + p*128] = pb[p];
        __syncthreads();
        if (cc + 16 < cend){
            int gc = cc + 16 + rho; if (gc >= cend) gc = cend - 1;
            const unsigned short* bp = xgh + (size_t)gc * FDIM;
#pragma unroll
            for (int p = 0; p < 4; p++)
                pb[p] = *(const short8v*)(bp + seg*8 + p*128);
        }

        f32x4v a00 = {0.f,0.f,0.f,0.f};
        f32x4v a01 = {0.f,0.f,0.f,0.f};
        f32x4v a10 = {0.f,0.f,0.f,0.f};
        f32x4v a11 = {0.f,0.f,0.f,0.f};
#pragma unroll
        for (int s = 0; s < 8; s++){
            short8v b0 = *(const short8v*)&Bs[lcol][lk*8 + s*32];
            short8v b1 = *(const short8v*)&Bs[lcol][lk*8 + (s+8)*32];
            a00 = __builtin_amdgcn_mfma_f32_16x16x32_bf16(aF0[s],   b0, a00, 0, 0, 0);
            a01 = __builtin_amdgcn_mfma_f32_16x16x32_bf16(aF0[s+8], b1, a01, 0, 0, 0);
            a10 = __builtin_amdgcn_mfma_f32_16x16x32_bf16(aF1[s],   b0, a10, 0, 0, 0);
            a11 = __builtin_amdgcn_mfma_f32_16x16x32_bf16(aF1[s+8], b1, a11, 0, 0, 0);
        }
        int gcol = cc + lcol;
        bool valid = gcol < cend;
        float rnc = valid ? rn[gcol] : 0.f;
#pragma unroll
        for (int i = 0; i < 4; i++){
            float v0 = valid ? (a00[i] + a01[i]) * rnc : -INFINITY;
            ins4(v0, gcol, tv[i],   ti[i]);
            float v1 = valid ? (a10[i] + a11[i]) * rnc : -INFINITY;
            ins4(v1, gcol, tv[4+i], ti[4+i]);
        }
    }

    // merge across the 16 col-class lanes -> per-row top-8 (8 row-slots).
    // Per-row interleave is lockstep-safe: both partners shuffle row i's
    // slots before either mutates row i.
    float mv[8][8]; int mi[8][8];
#pragma unroll
    for (int i=0;i<8;i++){
#pragma unroll
        for (int q=0;q<4;q++){ mv[i][q]=tv[i][q]; mi[i][q]=ti[i][q]; }
#pragma unroll
        for (int q=4;q<8;q++){ mv[i][q]=-INFINITY; mi[i][q]=INT_MAX; }
    }
#pragma unroll
    for (int mask=1; mask<16; mask<<=1){
#pragma unroll
        for (int i=0;i<8;i++){
            float ov[8]; int oi[8];
#pragma unroll
            for (int q=0;q<8;q++){
                ov[q] = __shfl_xor(mv[i][q], mask);
                oi[q] = __shfl_xor(mi[i][q], mask);
            }
#pragma unroll
            for (int q=0;q<8;q++)
                ins8(ov[q], oi[q], mv[i], mi[i]);
        }
    }
    if (lcol == 0){
#pragma unroll
        for (int i=0;i<8;i++){
            int grow = r0 + (i>>2)*16 + lk*4 + (i&3);
            if (grow < NNODE){
#pragma unroll
                for (int q=0;q<8;q++){
                    candV[((size_t)grow*BFSPLIT + split)*8 + q] = mv[i][q];
                    candI[((size_t)grow*BFSPLIT + split)*8 + q] = mi[i][q];
                }
            }
        }
    }
}

// ---------------------------------------------------------------------------
// exact rescore (validated structure, run once per 64-candidate half)
// ---------------------------------------------------------------------------
__global__ __launch_bounds__(256) void k_rescore(const float* __restrict__ xg,
        const float* __restrict__ rn, const float* __restrict__ candV,
        const int* __restrict__ candI, int half,
        float* __restrict__ htV, int* __restrict__ htI)
{
    __shared__ float Xr[4][512];        // 8 KB
    __shared__ float Cs[256][17];       // 17408 B
    __shared__ int   CrowS[256];        // 1 KB
    int t = threadIdx.x;
    int wv = t >> 6, lane = t & 63;
    int r0 = blockIdx.x * 4;
    int r  = r0 + wv;
    int cid = candI[(size_t)r*128 + half*64 + lane];
    float pv = candV[(size_t)r*128 + half*64 + lane];
    bool ok = (pv != -INFINITY) && (cid >= 0) && (cid < NNODE);
    int crow = ok ? cid : 0;
    CrowS[t] = crow;
    {
        int rr = t >> 6; int c = t & 63;
        const float* xp = xg + (size_t)(r0+rr)*FDIM;
        *(float4*)&Xr[rr][c*4]       = *(const float4*)(xp + c*4);
        *(float4*)&Xr[rr][256 + c*4] = *(const float4*)(xp + 256 + c*4);
    }
    float dot = 0.f;
    for (int kc = 0; kc < 512; kc += 16){
        __syncthreads();
#pragma unroll
        for (int p = 0; p < 4; p++){
            int slot = p*64 + (t >> 2);
            int f = t & 3;
            float4 v = *(const float4*)(xg + (size_t)CrowS[slot]*FDIM + kc + f*4);
            float* dst = &Cs[slot][f*4];
            dst[0]=v.x; dst[1]=v.y; dst[2]=v.z; dst[3]=v.w;
        }
        __syncthreads();
#pragma unroll
        for (int k2 = 0; k2 < 16; k2++)
            dot = fmaf(Xr[wv][kc + k2], Cs[t][k2], dot);
    }
    float v = ok ? (dot * rn[r]) * rn[crow] : -INFINITY;
    int id = ok ? cid : INT_MAX;
    float tvv[4]={-INFINITY,-INFINITY,-INFINITY,-INFINITY};
    int tii[4]={INT_MAX,INT_MAX,INT_MAX,INT_MAX};
    ins4(v, id, tvv, tii);
#pragma unroll
    for (int mask=1; mask<64; mask<<=1){
        float ov[4]; int oi[4];
#pragma unroll
        for (int s=0;s<4;s++){ ov[s]=__shfl_xor(tvv[s],mask); oi[s]=__shfl_xor(tii[s],mask); }
#pragma unroll
        for (int s=0;s<4;s++) ins4(ov[s], oi[s], tvv, tii);
    }
    if (lane == 0){
#pragma unroll
        for (int s=0;s<4;s++){ htV[r*8 + half*4 + s] = tvv[s]; htI[r*8 + half*4 + s] = tii[s]; }
    }
}

// merge the two exact half-top-4 lists (disjoint col ranges) -> global top-4
__global__ void k_hmerge(const float* __restrict__ htV, const int* __restrict__ htI,
        int* __restrict__ nbr){
    int r = blockIdx.x*256+threadIdx.x; if (r>=NNODE) return;
    float tv[4]={-INFINITY,-INFINITY,-INFINITY,-INFINITY};
    int ti[4]={INT_MAX,INT_MAX,INT_MAX,INT_MAX};
#pragma unroll
    for (int q=0;q<8;q++) ins4(htV[r*8+q], htI[r*8+q], tv, ti);
#pragma unroll
    for (int s=0;s<4;s++) nbr[r*4+s] = ti[s];
}

__global__ void k_eattr(const float* __restrict__ xg, const int* __restrict__ nbr, float* __restrict__ ea){
    int j = blockIdx.x; int t = threadIdx.x;
    int n0=nbr[j*4], n1=nbr[j*4+1], n2=nbr[j*4+2], n3=nbr[j*4+3];
    for (int d=t; d<FDIM; d+=256){
        float s = xg[(size_t)n0*FDIM+d]+xg[(size_t)n1*FDIM+d]+xg[(size_t)n2*FDIM+d]+xg[(size_t)n3*FDIM+d];
        ea[(size_t)j*FDIM+d] = 0.25f*s;
    }
}

__global__ void k_count(const int* __restrict__ nbr, int* __restrict__ counts){
    int e = blockIdx.x*256+threadIdx.x; if(e<NEDGE) atomicAdd(&counts[nbr[e]],1);
}

__global__ void k_scan(const int* __restrict__ counts, int* __restrict__ csrOff){
    __shared__ int part[257];
    int t=threadIdx.x;
    int start = t*33; int s=0;
    for (int i=0;i<33;i++){ int idx=start+i; if(idx<NNODE) s += counts[idx]; }
    part[t+1]=s; if(t==0) part[0]=0;
    __syncthreads();
    if (t==0){ for (int i=1;i<=256;i++) part[i]+=part[i-1]; }
    __syncthreads();
    int run = part[t];
    for (int i=0;i<33;i++){ int idx=start+i; if(idx<NNODE){ csrOff[idx]=run; run+=counts[idx]; } }
    if (t==255) csrOff[NNODE]=run;
}

__global__ void k_fill(const int* __restrict__ nbr, const int* __restrict__ csrOff,
        int* __restrict__ fillPos, int* __restrict__ csrE){
    int e = blockIdx.x*256+threadIdx.x; if(e>=NEDGE) return;
    int i = nbr[e];
    int p = atomicAdd(&fillPos[i],1);
    csrE[csrOff[i]+p] = e;
}

__global__ void k_alpha(const int* __restrict__ nbr, const float* __restrict__ ps,
        const float* __restrict__ pe, float* __restrict__ alphan){
    int e = blockIdx.x*256+threadIdx.x; if(e>=NEDGE) return;
    float a = ps[nbr[e]] + pe[e>>2];
    alphan[e] = a>=0.f? a : 0.2f*a;
}

__global__ void k_esm(const int* __restrict__ csrOff, const int* __restrict__ csrE,
        float* __restrict__ alphan){
    int i = blockIdx.x*256+threadIdx.x; if(i>=NNODE) return;
    int s0=csrOff[i], s1=csrOff[i+1];
    if (s1==s0) return;
    float m=-INFINITY;
    for (int s=s0;s<s1;s++) m = fmaxf(m, alphan[csrE[s]]);
    float Z=0.f;
    for (int s=s0;s<s1;s++) Z += __expf(alphan[csrE[s]]-m);
    float inv = 1.f/Z;
    for (int s=s0;s<s1;s++){ int e=csrE[s]; alphan[e] = __expf(alphan[e]-m)*inv; }
}

__global__ void k_oute(const float* __restrict__ xs, const float* __restrict__ alphan,
        const int* __restrict__ nbr, float* __restrict__ out_e){
    int j = blockIdx.x; int t=threadIdx.x;
    __shared__ float a[4]; __shared__ int sidx[4];
    if (t<4){ a[t]=alphan[j*4+t]; sidx[t]=nbr[j*4+t]; }
    __syncthreads();
    for (int d=t; d<FDIM; d+=256){
        float v = a[0]*xs[(size_t)sidx[0]*FDIM+d] + a[1]*xs[(size_t)sidx[1]*FDIM+d]
                + a[2]*xs[(size_t)sidx[2]*FDIM+d] + a[3]*xs[(size_t)sidx[3]*FDIM+d];
        out_e[(size_t)j*FDIM+d] = 0.25f*v;
    }
}

__global__ void k_outn(const float* __restrict__ out_e, const float* __restrict__ alphan,
        const int* __restrict__ csrOff, const int* __restrict__ csrE,
        const float* __restrict__ bias, float* __restrict__ out_n){
    int i = blockIdx.x; int t=threadIdx.x;
    int s0=csrOff[i], s1=csrOff[i+1];
    float Dinv = (s1>s0)? 1.f/(float)(s1-s0) : 0.f;
    for (int d=t; d<FDIM; d+=256){
        float accv=0.f;
        for (int s=s0;s<s1;s++){
            int e=csrE[s];
            accv = fmaf(alphan[e], out_e[(size_t)(e>>2)*FDIM+d], accv);
        }
        out_n[(size_t)i*FDIM+d] = bias[d] + Dinv*accv;
    }
}

__global__ void k_colstat1(const float* __restrict__ Xn, float* __restrict__ p1, float* __restrict__ p2){
    int b = blockIdx.x; int t=threadIdx.x;
    float s0=0,q0=0,s1=0,q1=0;
    for (int r=b; r<NNODE; r+=64){
        float v0 = Xn[(size_t)r*FDIM + t];
        float v1 = Xn[(size_t)r*FDIM + t + 256];
        s0+=v0; q0=fmaf(v0,v0,q0); s1+=v1; q1=fmaf(v1,v1,q1);
    }
    p1[b*FDIM+t]=s0; p1[b*FDIM+t+256]=s1;
    p2[b*FDIM+t]=q0; p2[b*FDIM+t+256]=q1;
}

__global__ void k_colstat2(const float* __restrict__ p1, const float* __restrict__ p2,
        const float* __restrict__ w, const float* __restrict__ sc,
        float* __restrict__ mu, float* __restrict__ g){
    int d = threadIdx.x + blockIdx.x*256; if(d>=FDIM) return;
    float s=0,q=0;
    for (int bb=0;bb<64;bb++){ s+=p1[bb*FDIM+d]; q+=p2[bb*FDIM+d]; }
    float m = s/(float)NNODE;
    float ms = m*sc[d];
    float var = q/(float)NNODE - 2.f*ms*m + ms*ms;
    mu[d]=m;
    g[d] = w[d]*rsqrtf(var+1e-5f);
}

__global__ void k_gnapply(const float* __restrict__ Xin, const float* __restrict__ mu,
        const float* __restrict__ g, const float* __restrict__ sc,
        const float* __restrict__ bb, float* __restrict__ Xout){
    size_t i = (size_t)blockIdx.x*256+threadIdx.x;
    if (i >= (size_t)NNODE*FDIM) return;
    int d = (int)(i & 511);
    float o = Xin[i] - mu[d]*sc[d];
    Xout[i] = lrelu(g[d]*o + bb[d], 0.01f);
}

__global__ void k_final(const float* __restrict__ x1, const float* __restrict__ x2,
        const float* __restrict__ f1W, const float* __restrict__ f1b,
        const float* __restrict__ f2W, const float* __restrict__ f2b,
        const float* __restrict__ clW, const float* __restrict__ clb,
        float* __restrict__ outp){
    int r = blockIdx.x;
    int h = threadIdx.x;
    __shared__ float o8[HIDN];
    float s1=f1b[h], s2=f2b[h];
    for (int k=0;k<FDIM;k++){
        s1 = fmaf(x1[(size_t)r*FDIM+k], f1W[(size_t)k*HIDN+h], s1);
        s2 = fmaf(x2[(size_t)r*FDIM+k], f2W[(size_t)k*HIDN+h], s2);
    }
    o8[h] = lrelu(s1,0.01f)+lrelu(s2,0.01f);
    __syncthreads();
    if (h < 2){
        float s = clb[h];
        for (int k=0;k<HIDN;k++) s = fmaf(o8[k], clW[k*2+h], s);
        outp[16 + r*2 + h] = s;
    }
}

// ---------------------------------------------------------------------------
extern "C" void kernel_launch(void* const* d_in, const int* in_sizes, int n_in,
                              void* d_out, int out_size, void* d_ws, size_t ws_size,
                              hipStream_t stream) {
    (void)in_sizes; (void)n_in; (void)out_size; (void)ws_size;
    const float* x    = (const float*)d_in[0];
    const float* reh  = (const float*)d_in[1];
    const float* aW1  = (const float*)d_in[2];
    const float* ab1  = (const float*)d_in[3];
    const float* aW2  = (const float*)d_in[4];
    const float* cW   = (const float*)d_in[6];
    const float* cb   = (const float*)d_in[7];
    const float* dW1  = (const float*)d_in[8];
    const float* db1  = (const float*)d_in[9];
    const float* dW2  = (const float*)d_in[10];
    const float* db2  = (const float*)d_in[11];
    const float* g1W  = (const float*)d_in[12];
    const float* g1att= (const float*)d_in[13];
    const float* g1b  = (const float*)d_in[14];
    const float* n1w  = (const float*)d_in[15];
    const float* n1b  = (const float*)d_in[16];
    const float* n1s  = (const float*)d_in[17];
    const float* f1W  = (const float*)d_in[18];
    const float* f1b  = (const float*)d_in[19];
    const float* g2W  = (const float*)d_in[20];
    const float* g2att= (const float*)d_in[21];
    const float* g2b  = (const float*)d_in[22];
    const float* n2w  = (const float*)d_in[23];
    const float* n2b  = (const float*)d_in[24];
    const float* n2s  = (const float*)d_in[25];
    const float* f2W  = (const float*)d_in[26];
    const float* f2b  = (const float*)d_in[27];
    const float* clW  = (const float*)d_in[28];
    const float* clb  = (const float*)d_in[29];
    float* out = (float*)d_out;
    char* ws = (char*)d_ws;

    // workspace layout (bytes)
    float* scores = (float*)(ws + 0);              // 524288
    float* Mbuf   = (float*)(ws + 524288);         // 16384
    float* xc     = (float*)(ws + 540672);         // 16793600  (later reused as xs)
    float* xg1    = (float*)(ws + 17334272);       // 8396800
    float* xg     = (float*)(ws + 25731072);       // 16793600  (later reused as x2)
    float* rn     = (float*)(ws + 42524672);       // 32800
    int*   nbrp   = (int*)  (ws + 44656896);       // 131200
    float* eattr  = (float*)(ws + 44788224);       // 16793600
    int*   counts = (int*)  (ws + 61581824);       // 32800
    int*   csrOff = (int*)  (ws + 61614848);       // 32804
    int*   fillPos= (int*)  (ws + 61647872);       // 32800
    int*   csrE   = (int*)  (ws + 61680896);       // 131200
    float* w2     = (float*)(ws + 61812096);       // 2048
    float* ps     = (float*)(ws + 61814144);       // 32800
    float* pe     = (float*)(ws + 61847040);       // 32800
    float* alphan = (float*)(ws + 61880064);       // 131200
    float* out_e  = (float*)(ws + 62011264);       // 16793600
    float* out_n  = (float*)(ws + 78804864);       // 16793600
    float* part1  = (float*)(ws + 95598464);       // 131072
    float* part2  = (float*)(ws + 95729536);       // 131072
    float* mu     = (float*)(ws + 95860608);       // 2048
    float* gsc    = (float*)(ws + 95862656);       // 2048
    float* x1buf  = (float*)(ws + 95864704);       // 16793600
    float* scoresP= (float*)(ws + 112658304);      // 2097152
    float* xs     = xc;      // alias (xc dead after xg1 GEMM)
    float* x2buf  = xg;      // alias (xg dead after layer-1 xs GEMM)
    float* MP     = scoresP;
    unsigned short* gW1hi = (unsigned short*)scoresP;                   // 524288
    unsigned short* gW1lo = (unsigned short*)((char*)scoresP + 524288); // 524288
    unsigned short* gW2hi = (unsigned short*)((char*)scoresP + 1048576);// 524288
    unsigned short* gW2lo = (unsigned short*)((char*)scoresP + 1572864);// 524288
    unsigned short* WThi = (unsigned short*)eattr;               // 524288 B
    unsigned short* WTlo = (unsigned short*)((char*)eattr + 524288); // 524288 B
    unsigned short* xgh = (unsigned short*)out_e;            // 8396800 B
    int*   candI = (int*)((char*)out_e + 8396800);           // 4198400 B
    int*   htI   = (int*)((char*)out_e + 12595200);          // 262400 B
    float* candV = out_n;                                    // 4198400 B
    float* htV   = (float*)((char*)out_n + 4198400);         // 262400 B

    hipMemsetAsync(counts, 0, NNODE*sizeof(int), stream);
    hipMemsetAsync(fillPos, 0, NNODE*sizeof(int), stream);

    // ---- attention MIL pooling ----
    k_wsplit<<<1024,256,0,stream>>>(aW1, WThi, WTlo);
    k_scores<<<dim3(4,1024),256,0,stream>>>(x, WThi, WTlo, ab1, aW2, scoresP);
    k_scred<<<512,256,0,stream>>>(scoresP, scores);
    k_softmax<<<NBAGS,256,0,stream>>>(scores);
    k_M<<<dim3(MCHUNK,NBAGS),256,0,stream>>>(x, scores, MP);
    k_Mred<<<NBAGS,512,0,stream>>>(MP, Mbuf);
    k_logits_mlp<<<1,64,0,stream>>>(Mbuf, cW, cb, out);

    // conv-layer weight splits (scoresP region is dead after k_Mred)
    k_wsplit<<<1024,256,0,stream>>>(g1W, gW1hi, gW1lo);
    k_wsplit<<<1024,256,0,stream>>>(g2W, gW2hi, gW2lo);

    // ---- projector (fp32: keeps xg bit-exact for the exact kNN rescore) ----
    k_xc<<<(NNODE*FDIM+255)/256,256,0,stream>>>(Mbuf, reh, xc);
    k_gemm<<<dim3(2,(NNODE+63)/64),256,0,stream>>>(xc, dW1, db1, xg1, nullptr, NNODE, HIDN, FDIM, 0.01f);
    k_gemm<<<dim3(4,(NNODE+63)/64),256,0,stream>>>(xg1, dW2, db2, xg, xgh, NNODE, FDIM, HIDN, 0.01f);

    // ---- kNN graph: bf16 MFMA prefilter + exact fp32 rescore ----
    k_rowdot<<<NNODE,64,0,stream>>>(xg, nullptr, rn, FDIM, 1);
    k_simbf<<<dim3(BFSPLIT,(NNODE+127)/128),256,0,stream>>>(xgh, rn, candV, candI);
    k_rescore<<<NNODE/4,256,0,stream>>>(xg, rn, candV, candI, 0, htV, htI);
    k_rescore<<<NNODE/4,256,0,stream>>>(xg, rn, candV, candI, 1, htV, htI);
    k_hmerge<<<(NNODE+255)/256,256,0,stream>>>(htV, htI, nbrp);
    k_eattr<<<NNODE,256,0,stream>>>(xg, nbrp, eattr);
    k_count<<<(NEDGE+255)/256,256,0,stream>>>(nbrp, counts);
    k_scan<<<1,256,0,stream>>>(counts, csrOff);
    k_fill<<<(NEDGE+255)/256,256,0,stream>>>(nbrp, csrOff, fillPos, csrE);

    // ---- two hypergraph conv layers (xs GEMM via bf16x3 MFMA) ----
    for (int layer=0; layer<2; ++layer){
        const float* Xin  = layer==0 ? xg   : x1buf;
        const float* W    = layer==0 ? g1W  : g2W;
        const unsigned short* Whi = layer==0 ? gW1hi : gW2hi;
        const unsigned short* Wlo = layer==0 ? gW1lo : gW2lo;
        const float* att  = layer==0 ? g1att: g2att;
        const float* gb   = layer==0 ? g1b  : g2b;
        const float* nw   = layer==0 ? n1w  : n2w;
        const float* nb_  = layer==0 ? n1b  : n2b;
        const float* ns   = layer==0 ? n1s  : n2s;
        float* Xout       = layer==0 ? x1buf: x2buf;

        k_gemm3<<<dim3(4,(NNODE+127)/128),256,0,stream>>>(Xin, Whi, Wlo, nullptr, xs, NNODE, FDIM, FDIM, 1.0f);
        k_watt<<<FDIM,64,0,stream>>>(W, att+FDIM, w2);
        k_rowdot<<<NNODE,64,0,stream>>>(xs, att, ps, FDIM, 0);
        k_rowdot<<<NNODE,64,0,stream>>>(eattr, w2, pe, FDIM, 0);
        k_alpha<<<(NEDGE+255)/256,256,0,stream>>>(nbrp, ps, pe, alphan);
        k_esm<<<(NNODE+255)/256,256,0,stream>>>(csrOff, csrE, alphan);
        k_oute<<<NNODE,256,0,stream>>>(xs, alphan, nbrp, out_e);
        k_outn<<<NNODE,256,0,stream>>>(out_e, alphan, csrOff, csrE, gb, out_n);
        k_colstat1<<<64,256,0,stream>>>(out_n, part1, part2);
        k_colstat2<<<2,256,0,stream>>>(part1, part2, nw, ns, mu, gsc);
        k_gnapply<<<(NNODE*FDIM+255)/256,256,0,stream>>>(out_n, mu, gsc, ns, nb_, Xout);
    }

    // ---- final heads (only rows 0..7 matter) ----
    k_final<<<NBAGS,HIDN,0,stream>>>(x1buf, x2buf, f1W, f1b, f2W, f2b, clW, clb, out);
}

// Round 17
// 1501.559 us; speedup vs baseline: 1.2662x; 1.2662x over previous
//
#include <hip/hip_runtime.h>
#include <math.h>
#include <limits.h>

#define FDIM 512
#define HIDN 256
#define NBAGS 8
#define NINST 16384
#define NNODE 8200
#define NEDGE 32800
#define BFSPLIT 16
#define SPLITW 513
#define MCHUNK 128

typedef __attribute__((ext_vector_type(8))) short short8v;   // 8 bf16 (4 VGPR)
typedef __attribute__((ext_vector_type(4))) float f32x4v;    // MFMA C/D frag

__device__ __forceinline__ float lrelu(float v, float s){ return v >= 0.f ? v : v*s; }

// sorted-4 insert with jax.lax.top_k tie semantics (lower index wins ties)
__device__ __forceinline__ void ins4(float v, int id, float* tv, int* ti){
    if ((v > tv[3]) || (v == tv[3] && id < ti[3])){
        tv[3]=v; ti[3]=id;
#pragma unroll
        for (int q=3;q>0;--q){
            bool sw = (tv[q] > tv[q-1]) || (tv[q]==tv[q-1] && ti[q]<ti[q-1]);
            if (sw){ float f=tv[q]; tv[q]=tv[q-1]; tv[q-1]=f; int d=ti[q]; ti[q]=ti[q-1]; ti[q-1]=d; }
        }
    }
}

__device__ __forceinline__ void ins8(float v, int id, float* tv, int* ti){
    if ((v > tv[7]) || (v == tv[7] && id < ti[7])){
        tv[7]=v; ti[7]=id;
#pragma unroll
        for (int q=7;q>0;--q){
            bool sw = (tv[q] > tv[q-1]) || (tv[q]==tv[q-1] && ti[q]<ti[q-1]);
            if (sw){ float f=tv[q]; tv[q]=tv[q-1]; tv[q-1]=f; int d=ti[q]; ti[q]=ti[q-1]; ti[q-1]=d; }
        }
    }
}

__device__ __forceinline__ unsigned short f2bf(float f){
    unsigned u = __float_as_uint(f);
    unsigned r = u + 0x7FFFu + ((u >> 16) & 1u);   // round-to-nearest-even
    return (unsigned short)(r >> 16);
}
__device__ __forceinline__ float bf2f(unsigned short h){
    return __uint_as_float((unsigned)h << 16);
}

// ---------------------------------------------------------------------------
// 512x512 weight split: WThi/WTlo[n][k] = bf16 hi/lo of W[k][n] (transposed)
// ---------------------------------------------------------------------------
__global__ void k_wsplit(const float* __restrict__ W,
        unsigned short* __restrict__ WThi, unsigned short* __restrict__ WTlo){
    int i = blockIdx.x*256 + threadIdx.x;          // i over 512*512
    int k = i >> 9, n = i & 511;
    float w = W[i];                                 // W[k][n]
    unsigned short hi = f2bf(w);
    unsigned short lo = f2bf(w - bf2f(hi));
    WThi[(size_t)n*512 + k] = hi;
    WTlo[(size_t)n*512 + k] = lo;
}

// ---------------------------------------------------------------------------
// scores via bf16x3 split MFMA (round-15 validated: LDS + register prefetch)
// ---------------------------------------------------------------------------
__global__ __launch_bounds__(256) void k_scores(const float* __restrict__ X,
        const unsigned short* __restrict__ WThi, const unsigned short* __restrict__ WTlo,
        const float* __restrict__ b1, const float* __restrict__ v2,
        float* __restrict__ scoresP)
{
    __shared__ unsigned short Ahi[128][40];
    __shared__ unsigned short Alo[128][40];
    __shared__ unsigned short Bhi[128][40];
    __shared__ unsigned short Blo[128][40];
    int t = threadIdx.x;
    int wv = t >> 6, lane = t & 63;
    int lcol = lane & 15, lk = lane >> 4;
    size_t mb = (size_t)blockIdx.y * 128;
    int nb = blockIdx.x * 128;

    f32x4v acc[2][8];
#pragma unroll
    for (int rf=0;rf<2;rf++)
#pragma unroll
        for (int cf=0;cf<8;cf++) acc[rf][cf] = (f32x4v){0.f,0.f,0.f,0.f};

    int segA = t & 7, rowA = t >> 3;
    int colB = t >> 2, partB = t & 3;

    float4 pa[4];
    short8v pwh[2], pwl[2];
#pragma unroll
    for (int q=0;q<4;q++)
        pa[q] = *(const float4*)(X + (mb + rowA + q*32)*512 + segA*4);
#pragma unroll
    for (int q=0;q<2;q++){
        int col = colB + q*64;
        pwh[q] = *(const short8v*)(WThi + (size_t)(nb+col)*512 + partB*8);
        pwl[q] = *(const short8v*)(WTlo + (size_t)(nb+col)*512 + partB*8);
    }

    for (int kc = 0; kc < 512; kc += 32){
        __syncthreads();
#pragma unroll
        for (int q=0;q<4;q++){
            float4 v = pa[q];
            ushort4 h, l;
            h.x=f2bf(v.x); h.y=f2bf(v.y); h.z=f2bf(v.z); h.w=f2bf(v.w);
            l.x=f2bf(v.x-bf2f(h.x)); l.y=f2bf(v.y-bf2f(h.y));
            l.z=f2bf(v.z-bf2f(h.z)); l.w=f2bf(v.w-bf2f(h.w));
            *(ushort4*)&Ahi[rowA + q*32][segA*4] = h;
            *(ushort4*)&Alo[rowA + q*32][segA*4] = l;
        }
#pragma unroll
        for (int q=0;q<2;q++){
            *(short8v*)&Bhi[colB + q*64][partB*8] = pwh[q];
            *(short8v*)&Blo[colB + q*64][partB*8] = pwl[q];
        }
        __syncthreads();
        if (kc + 32 < 512){
            int kn = kc + 32;
#pragma unroll
            for (int q=0;q<4;q++)
                pa[q] = *(const float4*)(X + (mb + rowA + q*32)*512 + kn + segA*4);
#pragma unroll
            for (int q=0;q<2;q++){
                int col = colB + q*64;
                pwh[q] = *(const short8v*)(WThi + (size_t)(nb+col)*512 + kn + partB*8);
                pwl[q] = *(const short8v*)(WTlo + (size_t)(nb+col)*512 + kn + partB*8);
            }
        }
        int r0 = wv*32;
        short8v ah0 = *(const short8v*)&Ahi[r0      + lcol][lk*8];
        short8v al0 = *(const short8v*)&Alo[r0      + lcol][lk*8];
        short8v ah1 = *(const short8v*)&Ahi[r0 + 16 + lcol][lk*8];
        short8v al1 = *(const short8v*)&Alo[r0 + 16 + lcol][lk*8];
#pragma unroll
        for (int cf=0; cf<8; cf++){
            short8v bh = *(const short8v*)&Bhi[cf*16 + lcol][lk*8];
            short8v bl = *(const short8v*)&Blo[cf*16 + lcol][lk*8];
            acc[0][cf] = __builtin_amdgcn_mfma_f32_16x16x32_bf16(ah0, bh, acc[0][cf], 0,0,0);
            acc[0][cf] = __builtin_amdgcn_mfma_f32_16x16x32_bf16(ah0, bl, acc[0][cf], 0,0,0);
            acc[0][cf] = __builtin_amdgcn_mfma_f32_16x16x32_bf16(al0, bh, acc[0][cf], 0,0,0);
            acc[1][cf] = __builtin_amdgcn_mfma_f32_16x16x32_bf16(ah1, bh, acc[1][cf], 0,0,0);
            acc[1][cf] = __builtin_amdgcn_mfma_f32_16x16x32_bf16(ah1, bl, acc[1][cf], 0,0,0);
            acc[1][cf] = __builtin_amdgcn_mfma_f32_16x16x32_bf16(al1, bh, acc[1][cf], 0,0,0);
        }
    }
    float rowsum[2][4];
#pragma unroll
    for (int rf=0;rf<2;rf++)
#pragma unroll
        for (int r=0;r<4;r++) rowsum[rf][r]=0.f;
#pragma unroll
    for (int rf=0; rf<2; rf++)
#pragma unroll
        for (int cf=0; cf<8; cf++){
            int gc = nb + cf*16 + lcol;
            float bb = b1[gc], vv = v2[gc];
#pragma unroll
            for (int r=0;r<4;r++){
                float h = acc[rf][cf][r] + bb;
                h = h > 0.f ? h : 0.f;
                rowsum[rf][r] = fmaf(h, vv, rowsum[rf][r]);
            }
        }
#pragma unroll
    for (int mask=1; mask<16; mask<<=1)
#pragma unroll
        for (int rf=0;rf<2;rf++)
#pragma unroll
            for (int r=0;r<4;r++)
                rowsum[rf][r] += __shfl_xor(rowsum[rf][r], mask);
    if (lcol == 0){
#pragma unroll
        for (int rf=0;rf<2;rf++)
#pragma unroll
            for (int r=0;r<4;r++){
                size_t grow = mb + wv*32 + rf*16 + lk*4 + r;
                scoresP[(size_t)blockIdx.x*(NBAGS*NINST) + grow] = rowsum[rf][r];
            }
    }
}

// ---------------------------------------------------------------------------
// generic bf16x3 MFMA GEMM (round-15 validated: LDS + register prefetch)
// ---------------------------------------------------------------------------
__global__ __launch_bounds__(256) void k_gemm3(const float* __restrict__ X,
        const unsigned short* __restrict__ WThi, const unsigned short* __restrict__ WTlo,
        const float* __restrict__ bias, float* __restrict__ C,
        int M, int N, int K, float slope)
{
    __shared__ unsigned short Ahi[128][40];
    __shared__ unsigned short Alo[128][40];
    __shared__ unsigned short Bhi[128][40];
    __shared__ unsigned short Blo[128][40];
    int t = threadIdx.x;
    int wv = t >> 6, lane = t & 63;
    int lcol = lane & 15, lk = lane >> 4;
    int mb = blockIdx.y * 128;
    int nb = blockIdx.x * 128;

    f32x4v acc[2][8];
#pragma unroll
    for (int rf=0;rf<2;rf++)
#pragma unroll
        for (int cf=0;cf<8;cf++) acc[rf][cf] = (f32x4v){0.f,0.f,0.f,0.f};

    int segA = t & 7, rowA = t >> 3;
    int colB = t >> 2, partB = t & 3;
    int grA[4];
#pragma unroll
    for (int q=0;q<4;q++){
        int gr = mb + rowA + q*32; if (gr >= M) gr = M-1;
        grA[q] = gr;
    }

    float4 pa[4];
    short8v pwh[2], pwl[2];
#pragma unroll
    for (int q=0;q<4;q++)
        pa[q] = *(const float4*)(X + (size_t)grA[q]*K + segA*4);
#pragma unroll
    for (int q=0;q<2;q++){
        int col = colB + q*64;
        pwh[q] = *(const short8v*)(WThi + (size_t)(nb+col)*K + partB*8);
        pwl[q] = *(const short8v*)(WTlo + (size_t)(nb+col)*K + partB*8);
    }

    for (int kc = 0; kc < K; kc += 32){
        __syncthreads();
#pragma unroll
        for (int q=0;q<4;q++){
            float4 v = pa[q];
            ushort4 h, l;
            h.x=f2bf(v.x); h.y=f2bf(v.y); h.z=f2bf(v.z); h.w=f2bf(v.w);
            l.x=f2bf(v.x-bf2f(h.x)); l.y=f2bf(v.y-bf2f(h.y));
            l.z=f2bf(v.z-bf2f(h.z)); l.w=f2bf(v.w-bf2f(h.w));
            *(ushort4*)&Ahi[rowA + q*32][segA*4] = h;
            *(ushort4*)&Alo[rowA + q*32][segA*4] = l;
        }
#pragma unroll
        for (int q=0;q<2;q++){
            *(short8v*)&Bhi[colB + q*64][partB*8] = pwh[q];
            *(short8v*)&Blo[colB + q*64][partB*8] = pwl[q];
        }
        __syncthreads();
        if (kc + 32 < K){
            int kn = kc + 32;
#pragma unroll
            for (int q=0;q<4;q++)
                pa[q] = *(const float4*)(X + (size_t)grA[q]*K + kn + segA*4);
#pragma unroll
            for (int q=0;q<2;q++){
                int col = colB + q*64;
                pwh[q] = *(const short8v*)(WThi + (size_t)(nb+col)*K + kn + partB*8);
                pwl[q] = *(const short8v*)(WTlo + (size_t)(nb+col)*K + kn + partB*8);
            }
        }
        int r0 = wv*32;
        short8v ah0 = *(const short8v*)&Ahi[r0      + lcol][lk*8];
        short8v al0 = *(const short8v*)&Alo[r0      + lcol][lk*8];
        short8v ah1 = *(const short8v*)&Ahi[r0 + 16 + lcol][lk*8];
        short8v al1 = *(const short8v*)&Alo[r0 + 16 + lcol][lk*8];
#pragma unroll
        for (int cf=0; cf<8; cf++){
            short8v bh = *(const short8v*)&Bhi[cf*16 + lcol][lk*8];
            short8v bl = *(const short8v*)&Blo[cf*16 + lcol][lk*8];
            acc[0][cf] = __builtin_amdgcn_mfma_f32_16x16x32_bf16(ah0, bh, acc[0][cf], 0,0,0);
            acc[0][cf] = __builtin_amdgcn_mfma_f32_16x16x32_bf16(ah0, bl, acc[0][cf], 0,0,0);
            acc[0][cf] = __builtin_amdgcn_mfma_f32_16x16x32_bf16(al0, bh, acc[0][cf], 0,0,0);
            acc[1][cf] = __builtin_amdgcn_mfma_f32_16x16x32_bf16(ah1, bh, acc[1][cf], 0,0,0);
            acc[1][cf] = __builtin_amdgcn_mfma_f32_16x16x32_bf16(ah1, bl, acc[1][cf], 0,0,0);
            acc[1][cf] = __builtin_amdgcn_mfma_f32_16x16x32_bf16(al1, bh, acc[1][cf], 0,0,0);
        }
    }
#pragma unroll
    for (int rf=0; rf<2; rf++)
#pragma unroll
        for (int cf=0; cf<8; cf++){
            int gc = nb + cf*16 + lcol;
            float bb = bias ? bias[gc] : 0.f;
#pragma unroll
            for (int r=0;r<4;r++){
                int grow = mb + wv*32 + rf*16 + lk*4 + r;
                if (grow < M){
                    float v = acc[rf][cf][r] + bb;
                    C[(size_t)grow*N + gc] = lrelu(v, slope);
                }
            }
        }
}

__global__ void k_scred(const float* __restrict__ sp, float* __restrict__ s){
    int r = blockIdx.x*256+threadIdx.x;
    if (r < NBAGS*NINST)
        s[r] = sp[r] + sp[NBAGS*NINST + r] + sp[2*NBAGS*NINST + r] + sp[3*NBAGS*NINST + r];
}

// softmax over 16384 per bag, in place
__global__ __launch_bounds__(256) void k_softmax(float* __restrict__ s0){
    int b = blockIdx.x; float* s = s0 + (size_t)b*NINST;
    __shared__ float red[256];
    int t = threadIdx.x;
    float m = -INFINITY;
    for (int i=t;i<NINST;i+=256) m = fmaxf(m, s[i]);
    red[t]=m; __syncthreads();
    for (int st=128; st>0; st>>=1){ if(t<st) red[t]=fmaxf(red[t],red[t+st]); __syncthreads(); }
    m = red[0]; __syncthreads();
    float sum=0.f;
    for (int i=t;i<NINST;i+=256) sum += __expf(s[i]-m);
    red[t]=sum; __syncthreads();
    for (int st=128; st>0; st>>=1){ if(t<st) red[t]+=red[t+st]; __syncthreads(); }
    float inv = 1.f/red[0];
    for (int i=t;i<NINST;i+=256) s[i] = __expf(s[i]-m)*inv;
}

// M partials: MP[(chunk*8+b)*512+d]; 128 chunks x 8 bags = 1024 blocks
__global__ __launch_bounds__(256) void k_M(const float* __restrict__ x,
        const float* __restrict__ A, float* __restrict__ MP){
    int b = blockIdx.y; int chunk = blockIdx.x;
    int n0 = chunk*(NINST/MCHUNK);
    __shared__ float As[NINST/MCHUNK];
    int t=threadIdx.x;
    if (t < NINST/MCHUNK) As[t] = A[(size_t)b*NINST+n0+t];
    __syncthreads();
    float a0=0.f, a1=0.f;
    const float* xb = x + ((size_t)b*NINST + n0)*FDIM;
    for (int n=0;n<NINST/MCHUNK;n++){
        float w = As[n];
        a0 = fmaf(w, xb[(size_t)n*FDIM + t],       a0);
        a1 = fmaf(w, xb[(size_t)n*FDIM + t + 256], a1);
    }
    MP[((size_t)chunk*NBAGS + b)*FDIM + t]       = a0;
    MP[((size_t)chunk*NBAGS + b)*FDIM + t + 256] = a1;
}

__global__ void k_Mred(const float* __restrict__ mp, float* __restrict__ M_){
    int b = blockIdx.x; int d = threadIdx.x; // 512 threads
    float s=0.f;
    for (int c=0;c<MCHUNK;c++) s += mp[((size_t)c*NBAGS+b)*FDIM + d];
    M_[b*FDIM+d]=s;
}

__global__ void k_logits_mlp(const float* __restrict__ M_, const float* __restrict__ cW,
        const float* __restrict__ cb, float* __restrict__ outp){
    int t = threadIdx.x;
    if (t < 16){
        int r=t>>1, c=t&1;
        float s=cb[c];
        for (int k=0;k<FDIM;k++) s = fmaf(M_[r*FDIM+k], cW[k*2+c], s);
        outp[r*2+c] = s;
    }
}

__global__ void k_xc(const float* __restrict__ M_, const float* __restrict__ reh, float* __restrict__ xc){
    size_t i = (size_t)blockIdx.x*256 + threadIdx.x;
    if (i >= (size_t)NNODE*FDIM) return;
    xc[i] = (i < (size_t)NBAGS*FDIM) ? M_[i] : reh[i - (size_t)NBAGS*FDIM];
}

// ---------------------------------------------------------------------------
// fp32 GEMM (projector only — keeps xg bit-exact for the exact kNN rescore)
// ---------------------------------------------------------------------------
__global__ __launch_bounds__(256) void k_gemm(const float* __restrict__ X,
        const float* __restrict__ W, const float* __restrict__ bias,
        float* __restrict__ C, unsigned short* __restrict__ Cbf,
        int M, int N, int K, float slope)
{
    __shared__ float As[32][68];
    __shared__ float Ws[32][128];
    int t = threadIdx.x; int tx = t & 15, ty = t >> 4;
    int mb = blockIdx.y * 64, nb = blockIdx.x * 128;
    float acc[4][8];
#pragma unroll
    for (int i=0;i<4;i++)
#pragma unroll
        for (int j=0;j<8;j++) acc[i][j]=0.f;

    int kq=(t&7)*4, m0=t>>3;
    int n4=(t&31)*4, k0=t>>5;
    for (int kc=0;kc<K;kc+=32){
#pragma unroll
        for (int mm=0;mm<2;mm++){
            int m = m0 + mm*32;
            int gr = mb + m; if (gr >= M) gr = M-1;
            float4 v = *(const float4*)(X + (size_t)gr*K + kc + kq);
            As[kq+0][m]=v.x; As[kq+1][m]=v.y; As[kq+2][m]=v.z; As[kq+3][m]=v.w;
        }
#pragma unroll
        for (int kk=0;kk<4;kk++){
            float4 v = *(const float4*)(W + (size_t)(kc+k0+kk*8)*N + nb + n4);
            *(float4*)&Ws[k0+kk*8][n4] = v;
        }
        __syncthreads();
#pragma unroll 4
        for (int k=0;k<32;k++){
            float4 a = *(const float4*)&As[k][ty*4];
            float4 b0 = *(const float4*)&Ws[k][tx*4];
            float4 b1 = *(const float4*)&Ws[k][64+tx*4];
            float av[4]={a.x,a.y,a.z,a.w};
            float bv[8]={b0.x,b0.y,b0.z,b0.w,b1.x,b1.y,b1.z,b1.w};
#pragma unroll
            for (int i=0;i<4;i++)
#pragma unroll
                for (int j=0;j<8;j++)
                    acc[i][j] = fmaf(av[i], bv[j], acc[i][j]);
        }
        __syncthreads();
    }
#pragma unroll
    for (int i=0;i<4;i++){
        int gr = mb + ty*4 + i;
        if (gr >= M) continue;
        float o[8];
#pragma unroll
        for (int j=0;j<8;j++){
            int gc = (j<4) ? (nb + tx*4 + j) : (nb + 64 + tx*4 + (j-4));
            float v = acc[i][j] + (bias ? bias[gc] : 0.f);
            o[j] = lrelu(v, slope);
        }
        float4 o0 = make_float4(o[0],o[1],o[2],o[3]);
        float4 o1 = make_float4(o[4],o[5],o[6],o[7]);
        *(float4*)(C + (size_t)gr*N + nb + tx*4)      = o0;
        *(float4*)(C + (size_t)gr*N + nb + 64 + tx*4) = o1;
        if (Cbf){
            ushort4 h0, h1;
            h0.x=f2bf(o[0]); h0.y=f2bf(o[1]); h0.z=f2bf(o[2]); h0.w=f2bf(o[3]);
            h1.x=f2bf(o[4]); h1.y=f2bf(o[5]); h1.z=f2bf(o[6]); h1.w=f2bf(o[7]);
            *(ushort4*)(Cbf + (size_t)gr*N + nb + tx*4)      = h0;
            *(ushort4*)(Cbf + (size_t)gr*N + nb + 64 + tx*4) = h1;
        }
    }
}

// row dot: mode 0: out[r] = X[r]·v ; mode 1: out[r] = 1/(sqrt(X[r]·X[r])+1e-12)
__global__ void k_rowdot(const float* __restrict__ X, const float* __restrict__ v,
        float* __restrict__ out, int K, int mode){
    int r = blockIdx.x; int t = threadIdx.x;
    const float* xr = X + (size_t)r*K;
    float s = 0.f;
    if (mode==1){ for (int k=t;k<K;k+=64){ float x_=xr[k]; s=fmaf(x_,x_,s);} }
    else        { for (int k=t;k<K;k+=64) s=fmaf(xr[k],v[k],s); }
    for (int off=32;off;off>>=1) s += __shfl_down(s, off);
    if (t==0) out[r] = (mode==1)? 1.f/(sqrtf(s)+1e-12f) : s;
}

// w2[k] = sum_j W[k][j]*att2[j]
__global__ void k_watt(const float* __restrict__ W, const float* __restrict__ att2, float* __restrict__ w2){
    int k = blockIdx.x; int t=threadIdx.x;
    float s=0.f;
    for (int j=t;j<FDIM;j+=64) s=fmaf(W[(size_t)k*FDIM+j], att2[j], s);
    for (int off=32;off;off>>=1) s += __shfl_down(s, off);
    if (t==0) w2[k]=s;
}

// ---------------------------------------------------------------------------
// bf16 MFMA prefilter (round-15 validated verbatim: 16 rows/wave, LDS +
// register prefetch, dual split-K accumulators, 16 splits x 513 cols).
// Round-16's 32-row variant regressed (occupancy 28->10%); reverted.
// ---------------------------------------------------------------------------
__global__ __launch_bounds__(256) void k_simbf(const unsigned short* __restrict__ xgh,
        const float* __restrict__ rn, float* __restrict__ candV, int* __restrict__ candI)
{
    __shared__ unsigned short Bs[16][520];
    int t = threadIdx.x;
    int wv = t >> 6, lane = t & 63;
    int lcol = lane & 15, lk = lane >> 4;
    int split = blockIdx.x;
    int r0 = blockIdx.y * 64 + wv * 16;

    short8v aF[16];
    {
        int arow = r0 + lcol; if (arow >= NNODE) arow = NNODE - 1;
        const unsigned short* ap = xgh + (size_t)arow * FDIM + lk * 8;
#pragma unroll
        for (int s = 0; s < 16; s++)
            aF[s] = *(const short8v*)(ap + s * 32);
    }

    int c0 = split * SPLITW;
    int cend = c0 + SPLITW; if (cend > NNODE) cend = NNODE;

    float tv[4][4]; int ti[4][4];
#pragma unroll
    for (int i=0;i<4;i++)
#pragma unroll
        for (int q=0;q<4;q++){ tv[i][q]=-INFINITY; ti[i][q]=INT_MAX; }

    int rho = t >> 4, seg = t & 15;

    short8v pb[4];
    {
        int gc = c0 + rho; if (gc >= cend) gc = cend - 1;
        const unsigned short* bp = xgh + (size_t)gc * FDIM;
#pragma unroll
        for (int p = 0; p < 4; p++)
            pb[p] = *(const short8v*)(bp + seg*8 + p*128);
    }

    for (int cc = c0; cc < cend; cc += 16){
        __syncthreads();
#pragma unroll
        for (int p = 0; p < 4; p++)
            *(short8v*)&Bs[rho][seg*8 + p*128] = pb[p];
        __syncthreads();
        if (cc + 16 < cend){
            int gc = cc + 16 + rho; if (gc >= cend) gc = cend - 1;
            const unsigned short* bp = xgh + (size_t)gc * FDIM;
#pragma unroll
            for (int p = 0; p < 4; p++)
                pb[p] = *(const short8v*)(bp + seg*8 + p*128);
        }

        f32x4v acc0 = {0.f,0.f,0.f,0.f};
        f32x4v acc1 = {0.f,0.f,0.f,0.f};
#pragma unroll
        for (int s = 0; s < 8; s++){
            short8v b0 = *(const short8v*)&Bs[lcol][lk*8 + s*32];
            short8v b1 = *(const short8v*)&Bs[lcol][lk*8 + (s+8)*32];
            acc0 = __builtin_amdgcn_mfma_f32_16x16x32_bf16(aF[s],   b0, acc0, 0, 0, 0);
            acc1 = __builtin_amdgcn_mfma_f32_16x16x32_bf16(aF[s+8], b1, acc1, 0, 0, 0);
        }
        int gcol = cc + lcol;
        bool valid = gcol < cend;
        float rnc = valid ? rn[gcol] : 0.f;
#pragma unroll
        for (int i = 0; i < 4; i++){
            float v = valid ? (acc0[i] + acc1[i]) * rnc : -INFINITY;
            ins4(v, gcol, tv[i], ti[i]);
        }
    }

    float mv[4][8]; int mi[4][8];
#pragma unroll
    for (int i=0;i<4;i++){
#pragma unroll
        for (int q=0;q<4;q++){ mv[i][q]=tv[i][q]; mi[i][q]=ti[i][q]; }
#pragma unroll
        for (int q=4;q<8;q++){ mv[i][q]=-INFINITY; mi[i][q]=INT_MAX; }
    }
#pragma unroll
    for (int mask=1; mask<16; mask<<=1){
        float ov[4][8]; int oi[4][8];
#pragma unroll
        for (int i=0;i<4;i++)
#pragma unroll
            for (int q=0;q<8;q++){
                ov[i][q] = __shfl_xor(mv[i][q], mask);
                oi[i][q] = __shfl_xor(mi[i][q], mask);
            }
#pragma unroll
        for (int i=0;i<4;i++)
#pragma unroll
            for (int q=0;q<8;q++)
                ins8(ov[i][q], oi[i][q], mv[i], mi[i]);
    }
    if (lcol == 0){
#pragma unroll
        for (int i=0;i<4;i++){
            int grow = r0 + lk*4 + i;
            if (grow < NNODE){
#pragma unroll
                for (int q=0;q<8;q++){
                    candV[((size_t)grow*BFSPLIT + split)*8 + q] = mv[i][q];
                    candI[((size_t)grow*BFSPLIT + split)*8 + q] = mi[i][q];
                }
            }
        }
    }
}

// ---------------------------------------------------------------------------
// exact rescore (validated structure); both 64-candidate halves launched as
// one grid (blockIdx.y = half) so they overlap instead of running serially.
// Per-half computation identical; disjoint htV/htI outputs -> bit-exact.
// ---------------------------------------------------------------------------
__global__ __launch_bounds__(256) void k_rescore(const float* __restrict__ xg,
        const float* __restrict__ rn, const float* __restrict__ candV,
        const int* __restrict__ candI,
        float* __restrict__ htV, int* __restrict__ htI)
{
    __shared__ float Xr[4][512];        // 8 KB
    __shared__ float Cs[256][17];       // 17408 B
    __shared__ int   CrowS[256];        // 1 KB
    int t = threadIdx.x;
    int wv = t >> 6, lane = t & 63;
    int half = blockIdx.y;
    int r0 = blockIdx.x * 4;
    int r  = r0 + wv;
    int cid = candI[(size_t)r*128 + half*64 + lane];
    float pv = candV[(size_t)r*128 + half*64 + lane];
    bool ok = (pv != -INFINITY) && (cid >= 0) && (cid < NNODE);
    int crow = ok ? cid : 0;
    CrowS[t] = crow;
    {
        int rr = t >> 6; int c = t & 63;
        const float* xp = xg + (size_t)(r0+rr)*FDIM;
        *(float4*)&Xr[rr][c*4]       = *(const float4*)(xp + c*4);
        *(float4*)&Xr[rr][256 + c*4] = *(const float4*)(xp + 256 + c*4);
    }
    float dot = 0.f;
    for (int kc = 0; kc < 512; kc += 16){
        __syncthreads();
#pragma unroll
        for (int p = 0; p < 4; p++){
            int slot = p*64 + (t >> 2);
            int f = t & 3;
            float4 v = *(const float4*)(xg + (size_t)CrowS[slot]*FDIM + kc + f*4);
            float* dst = &Cs[slot][f*4];
            dst[0]=v.x; dst[1]=v.y; dst[2]=v.z; dst[3]=v.w;
        }
        __syncthreads();
#pragma unroll
        for (int k2 = 0; k2 < 16; k2++)
            dot = fmaf(Xr[wv][kc + k2], Cs[t][k2], dot);
    }
    float v = ok ? (dot * rn[r]) * rn[crow] : -INFINITY;
    int id = ok ? cid : INT_MAX;
    float tvv[4]={-INFINITY,-INFINITY,-INFINITY,-INFINITY};
    int tii[4]={INT_MAX,INT_MAX,INT_MAX,INT_MAX};
    ins4(v, id, tvv, tii);
#pragma unroll
    for (int mask=1; mask<64; mask<<=1){
        float ov[4]; int oi[4];
#pragma unroll
        for (int s=0;s<4;s++){ ov[s]=__shfl_xor(tvv[s],mask); oi[s]=__shfl_xor(tii[s],mask); }
#pragma unroll
        for (int s=0;s<4;s++) ins4(ov[s], oi[s], tvv, tii);
    }
    if (lane == 0){
#pragma unroll
        for (int s=0;s<4;s++){ htV[r*8 + half*4 + s] = tvv[s]; htI[r*8 + half*4 + s] = tii[s]; }
    }
}

// merge the two exact half-top-4 lists (disjoint col ranges) -> global top-4
__global__ void k_hmerge(const float* __restrict__ htV, const int* __restrict__ htI,
        int* __restrict__ nbr){
    int r = blockIdx.x*256+threadIdx.x; if (r>=NNODE) return;
    float tv[4]={-INFINITY,-INFINITY,-INFINITY,-INFINITY};
    int ti[4]={INT_MAX,INT_MAX,INT_MAX,INT_MAX};
#pragma unroll
    for (int q=0;q<8;q++) ins4(htV[r*8+q], htI[r*8+q], tv, ti);
#pragma unroll
    for (int s=0;s<4;s++) nbr[r*4+s] = ti[s];
}

__global__ void k_eattr(const float* __restrict__ xg, const int* __restrict__ nbr, float* __restrict__ ea){
    int j = blockIdx.x; int t = threadIdx.x;
    int n0=nbr[j*4], n1=nbr[j*4+1], n2=nbr[j*4+2], n3=nbr[j*4+3];
    for (int d=t; d<FDIM; d+=256){
        float s = xg[(size_t)n0*FDIM+d]+xg[(size_t)n1*FDIM+d]+xg[(size_t)n2*FDIM+d]+xg[(size_t)n3*FDIM+d];
        ea[(size_t)j*FDIM+d] = 0.25f*s;
    }
}

__global__ void k_count(const int* __restrict__ nbr, int* __restrict__ counts){
    int e = blockIdx.x*256+threadIdx.x; if(e<NEDGE) atomicAdd(&counts[nbr[e]],1);
}

__global__ void k_scan(const int* __restrict__ counts, int* __restrict__ csrOff){
    __shared__ int part[257];
    int t=threadIdx.x;
    int start = t*33; int s=0;
    for (int i=0;i<33;i++){ int idx=start+i; if(idx<NNODE) s += counts[idx]; }
    part[t+1]=s; if(t==0) part[0]=0;
    __syncthreads();
    if (t==0){ for (int i=1;i<=256;i++) part[i]+=part[i-1]; }
    __syncthreads();
    int run = part[t];
    for (int i=0;i<33;i++){ int idx=start+i; if(idx<NNODE){ csrOff[idx]=run; run+=counts[idx]; } }
    if (t==255) csrOff[NNODE]=run;
}

__global__ void k_fill(const int* __restrict__ nbr, const int* __restrict__ csrOff,
        int* __restrict__ fillPos, int* __restrict__ csrE){
    int e = blockIdx.x*256+threadIdx.x; if(e>=NEDGE) return;
    int i = nbr[e];
    int p = atomicAdd(&fillPos[i],1);
    csrE[csrOff[i]+p] = e;
}

__global__ void k_alpha(const int* __restrict__ nbr, const float* __restrict__ ps,
        const float* __restrict__ pe, float* __restrict__ alphan){
    int e = blockIdx.x*256+threadIdx.x; if(e>=NEDGE) return;
    float a = ps[nbr[e]] + pe[e>>2];
    alphan[e] = a>=0.f? a : 0.2f*a;
}

__global__ void k_esm(const int* __restrict__ csrOff, const int* __restrict__ csrE,
        float* __restrict__ alphan){
    int i = blockIdx.x*256+threadIdx.x; if(i>=NNODE) return;
    int s0=csrOff[i], s1=csrOff[i+1];
    if (s1==s0) return;
    float m=-INFINITY;
    for (int s=s0;s<s1;s++) m = fmaxf(m, alphan[csrE[s]]);
    float Z=0.f;
    for (int s=s0;s<s1;s++) Z += __expf(alphan[csrE[s]]-m);
    float inv = 1.f/Z;
    for (int s=s0;s<s1;s++){ int e=csrE[s]; alphan[e] = __expf(alphan[e]-m)*inv; }
}

__global__ void k_oute(const float* __restrict__ xs, const float* __restrict__ alphan,
        const int* __restrict__ nbr, float* __restrict__ out_e){
    int j = blockIdx.x; int t=threadIdx.x;
    __shared__ float a[4]; __shared__ int sidx[4];
    if (t<4){ a[t]=alphan[j*4+t]; sidx[t]=nbr[j*4+t]; }
    __syncthreads();
    for (int d=t; d<FDIM; d+=256){
        float v = a[0]*xs[(size_t)sidx[0]*FDIM+d] + a[1]*xs[(size_t)sidx[1]*FDIM+d]
                + a[2]*xs[(size_t)sidx[2]*FDIM+d] + a[3]*xs[(size_t)sidx[3]*FDIM+d];
        out_e[(size_t)j*FDIM+d] = 0.25f*v;
    }
}

__global__ void k_outn(const float* __restrict__ out_e, const float* __restrict__ alphan,
        const int* __restrict__ csrOff, const int* __restrict__ csrE,
        const float* __restrict__ bias, float* __restrict__ out_n){
    int i = blockIdx.x; int t=threadIdx.x;
    int s0=csrOff[i], s1=csrOff[i+1];
    float Dinv = (s1>s0)? 1.f/(float)(s1-s0) : 0.f;
    for (int d=t; d<FDIM; d+=256){
        float accv=0.f;
        for (int s=s0;s<s1;s++){
            int e=csrE[s];
            accv = fmaf(alphan[e], out_e[(size_t)(e>>2)*FDIM+d], accv);
        }
        out_n[(size_t)i*FDIM+d] = bias[d] + Dinv*accv;
    }
}

__global__ void k_colstat1(const float* __restrict__ Xn, float* __restrict__ p1, float* __restrict__ p2){
    int b = blockIdx.x; int t=threadIdx.x;
    float s0=0,q0=0,s1=0,q1=0;
    for (int r=b; r<NNODE; r+=64){
        float v0 = Xn[(size_t)r*FDIM + t];
        float v1 = Xn[(size_t)r*FDIM + t + 256];
        s0+=v0; q0=fmaf(v0,v0,q0); s1+=v1; q1=fmaf(v1,v1,q1);
    }
    p1[b*FDIM+t]=s0; p1[b*FDIM+t+256]=s1;
    p2[b*FDIM+t]=q0; p2[b*FDIM+t+256]=q1;
}

__global__ void k_colstat2(const float* __restrict__ p1, const float* __restrict__ p2,
        const float* __restrict__ w, const float* __restrict__ sc,
        float* __restrict__ mu, float* __restrict__ g){
    int d = threadIdx.x + blockIdx.x*256; if(d>=FDIM) return;
    float s=0,q=0;
    for (int bb=0;bb<64;bb++){ s+=p1[bb*FDIM+d]; q+=p2[bb*FDIM+d]; }
    float m = s/(float)NNODE;
    float ms = m*sc[d];
    float var = q/(float)NNODE - 2.f*ms*m + ms*ms;
    mu[d]=m;
    g[d] = w[d]*rsqrtf(var+1e-5f);
}

__global__ void k_gnapply(const float* __restrict__ Xin, const float* __restrict__ mu,
        const float* __restrict__ g, const float* __restrict__ sc,
        const float* __restrict__ bb, float* __restrict__ Xout){
    size_t i = (size_t)blockIdx.x*256+threadIdx.x;
    if (i >= (size_t)NNODE*FDIM) return;
    int d = (int)(i & 511);
    float o = Xin[i] - mu[d]*sc[d];
    Xout[i] = lrelu(g[d]*o + bb[d], 0.01f);
}

__global__ void k_final(const float* __restrict__ x1, const float* __restrict__ x2,
        const float* __restrict__ f1W, const float* __restrict__ f1b,
        const float* __restrict__ f2W, const float* __restrict__ f2b,
        const float* __restrict__ clW, const float* __restrict__ clb,
        float* __restrict__ outp){
    int r = blockIdx.x;
    int h = threadIdx.x;
    __shared__ float o8[HIDN];
    float s1=f1b[h], s2=f2b[h];
    for (int k=0;k<FDIM;k++){
        s1 = fmaf(x1[(size_t)r*FDIM+k], f1W[(size_t)k*HIDN+h], s1);
        s2 = fmaf(x2[(size_t)r*FDIM+k], f2W[(size_t)k*HIDN+h], s2);
    }
    o8[h] = lrelu(s1,0.01f)+lrelu(s2,0.01f);
    __syncthreads();
    if (h < 2){
        float s = clb[h];
        for (int k=0;k<HIDN;k++) s = fmaf(o8[k], clW[k*2+h], s);
        outp[16 + r*2 + h] = s;
    }
}

// ---------------------------------------------------------------------------
extern "C" void kernel_launch(void* const* d_in, const int* in_sizes, int n_in,
                              void* d_out, int out_size, void* d_ws, size_t ws_size,
                              hipStream_t stream) {
    (void)in_sizes; (void)n_in; (void)out_size; (void)ws_size;
    const float* x    = (const float*)d_in[0];
    const float* reh  = (const float*)d_in[1];
    const float* aW1  = (const float*)d_in[2];
    const float* ab1  = (const float*)d_in[3];
    const float* aW2  = (const float*)d_in[4];
    const float* cW   = (const float*)d_in[6];
    const float* cb   = (const float*)d_in[7];
    const float* dW1  = (const float*)d_in[8];
    const float* db1  = (const float*)d_in[9];
    const float* dW2  = (const float*)d_in[10];
    const float* db2  = (const float*)d_in[11];
    const float* g1W  = (const float*)d_in[12];
    const float* g1att= (const float*)d_in[13];
    const float* g1b  = (const float*)d_in[14];
    const float* n1w  = (const float*)d_in[15];
    const float* n1b  = (const float*)d_in[16];
    const float* n1s  = (const float*)d_in[17];
    const float* f1W  = (const float*)d_in[18];
    const float* f1b  = (const float*)d_in[19];
    const float* g2W  = (const float*)d_in[20];
    const float* g2att= (const float*)d_in[21];
    const float* g2b  = (const float*)d_in[22];
    const float* n2w  = (const float*)d_in[23];
    const float* n2b  = (const float*)d_in[24];
    const float* n2s  = (const float*)d_in[25];
    const float* f2W  = (const float*)d_in[26];
    const float* f2b  = (const float*)d_in[27];
    const float* clW  = (const float*)d_in[28];
    const float* clb  = (const float*)d_in[29];
    float* out = (float*)d_out;
    char* ws = (char*)d_ws;

    // workspace layout (bytes)
    float* scores = (float*)(ws + 0);              // 524288
    float* Mbuf   = (float*)(ws + 524288);         // 16384
    float* xc     = (float*)(ws + 540672);         // 16793600  (later reused as xs)
    float* xg1    = (float*)(ws + 17334272);       // 8396800
    float* xg     = (float*)(ws + 25731072);       // 16793600  (later reused as x2)
    float* rn     = (float*)(ws + 42524672);       // 32800
    int*   nbrp   = (int*)  (ws + 44656896);       // 131200
    float* eattr  = (float*)(ws + 44788224);       // 16793600
    int*   counts = (int*)  (ws + 61581824);       // 32800
    int*   csrOff = (int*)  (ws + 61614848);       // 32804
    int*   fillPos= (int*)  (ws + 61647872);       // 32800
    int*   csrE   = (int*)  (ws + 61680896);       // 131200
    float* w2     = (float*)(ws + 61812096);       // 2048
    float* ps     = (float*)(ws + 61814144);       // 32800
    float* pe     = (float*)(ws + 61847040);       // 32800
    float* alphan = (float*)(ws + 61880064);       // 131200
    float* out_e  = (float*)(ws + 62011264);       // 16793600
    float* out_n  = (float*)(ws + 78804864);       // 16793600
    float* part1  = (float*)(ws + 95598464);       // 131072
    float* part2  = (float*)(ws + 95729536);       // 131072
    float* mu     = (float*)(ws + 95860608);       // 2048
    float* gsc    = (float*)(ws + 95862656);       // 2048
    float* x1buf  = (float*)(ws + 95864704);       // 16793600
    float* scoresP= (float*)(ws + 112658304);      // 2097152
    float* xs     = xc;      // alias (xc dead after xg1 GEMM)
    float* x2buf  = xg;      // alias (xg dead after layer-1 xs GEMM)
    float* MP     = scoresP;
    unsigned short* gW1hi = (unsigned short*)scoresP;                   // 524288
    unsigned short* gW1lo = (unsigned short*)((char*)scoresP + 524288); // 524288
    unsigned short* gW2hi = (unsigned short*)((char*)scoresP + 1048576);// 524288
    unsigned short* gW2lo = (unsigned short*)((char*)scoresP + 1572864);// 524288
    unsigned short* WThi = (unsigned short*)eattr;               // 524288 B
    unsigned short* WTlo = (unsigned short*)((char*)eattr + 524288); // 524288 B
    unsigned short* xgh = (unsigned short*)out_e;            // 8396800 B
    int*   candI = (int*)((char*)out_e + 8396800);           // 4198400 B
    int*   htI   = (int*)((char*)out_e + 12595200);          // 262400 B
    float* candV = out_n;                                    // 4198400 B
    float* htV   = (float*)((char*)out_n + 4198400);         // 262400 B

    hipMemsetAsync(counts, 0, NNODE*sizeof(int), stream);
    hipMemsetAsync(fillPos, 0, NNODE*sizeof(int), stream);

    // ---- attention MIL pooling ----
    k_wsplit<<<1024,256,0,stream>>>(aW1, WThi, WTlo);
    k_scores<<<dim3(4,1024),256,0,stream>>>(x, WThi, WTlo, ab1, aW2, scoresP);
    k_scred<<<512,256,0,stream>>>(scoresP, scores);
    k_softmax<<<NBAGS,256,0,stream>>>(scores);
    k_M<<<dim3(MCHUNK,NBAGS),256,0,stream>>>(x, scores, MP);
    k_Mred<<<NBAGS,512,0,stream>>>(MP, Mbuf);
    k_logits_mlp<<<1,64,0,stream>>>(Mbuf, cW, cb, out);

    // conv-layer weight splits (scoresP region is dead after k_Mred)
    k_wsplit<<<1024,256,0,stream>>>(g1W, gW1hi, gW1lo);
    k_wsplit<<<1024,256,0,stream>>>(g2W, gW2hi, gW2lo);

    // ---- projector (fp32: keeps xg bit-exact for the exact kNN rescore) ----
    k_xc<<<(NNODE*FDIM+255)/256,256,0,stream>>>(Mbuf, reh, xc);
    k_gemm<<<dim3(2,(NNODE+63)/64),256,0,stream>>>(xc, dW1, db1, xg1, nullptr, NNODE, HIDN, FDIM, 0.01f);
    k_gemm<<<dim3(4,(NNODE+63)/64),256,0,stream>>>(xg1, dW2, db2, xg, xgh, NNODE, FDIM, HIDN, 0.01f);

    // ---- kNN graph: bf16 MFMA prefilter + exact fp32 rescore ----
    k_rowdot<<<NNODE,64,0,stream>>>(xg, nullptr, rn, FDIM, 1);
    k_simbf<<<dim3(BFSPLIT,(NNODE+63)/64),256,0,stream>>>(xgh, rn, candV, candI);
    k_rescore<<<dim3(NNODE/4,2),256,0,stream>>>(xg, rn, candV, candI, htV, htI);
    k_hmerge<<<(NNODE+255)/256,256,0,stream>>>(htV, htI, nbrp);
    k_eattr<<<NNODE,256,0,stream>>>(xg, nbrp, eattr);
    k_count<<<(NEDGE+255)/256,256,0,stream>>>(nbrp, counts);
    k_scan<<<1,256,0,stream>>>(counts, csrOff);
    k_fill<<<(NEDGE+255)/256,256,0,stream>>>(nbrp, csrOff, fillPos, csrE);

    // ---- two hypergraph conv layers (xs GEMM via bf16x3 MFMA) ----
    for (int layer=0; layer<2; ++layer){
        const float* Xin  = layer==0 ? xg   : x1buf;
        const float* W    = layer==0 ? g1W  : g2W;
        const unsigned short* Whi = layer==0 ? gW1hi : gW2hi;
        const unsigned short* Wlo = layer==0 ? gW1lo : gW2lo;
        const float* att  = layer==0 ? g1att: g2att;
        const float* gb   = layer==0 ? g1b  : g2b;
        const float* nw   = layer==0 ? n1w  : n2w;
        const float* nb_  = layer==0 ? n1b  : n2b;
        const float* ns   = layer==0 ? n1s  : n2s;
        float* Xout       = layer==0 ? x1buf: x2buf;

        k_gemm3<<<dim3(4,(NNODE+127)/128),256,0,stream>>>(Xin, Whi, Wlo, nullptr, xs, NNODE, FDIM, FDIM, 1.0f);
        k_watt<<<FDIM,64,0,stream>>>(W, att+FDIM, w2);
        k_rowdot<<<NNODE,64,0,stream>>>(xs, att, ps, FDIM, 0);
        k_rowdot<<<NNODE,64,0,stream>>>(eattr, w2, pe, FDIM, 0);
        k_alpha<<<(NEDGE+255)/256,256,0,stream>>>(nbrp, ps, pe, alphan);
        k_esm<<<(NNODE+255)/256,256,0,stream>>>(csrOff, csrE, alphan);
        k_oute<<<NNODE,256,0,stream>>>(xs, alphan, nbrp, out_e);
        k_outn<<<NNODE,256,0,stream>>>(out_e, alphan, csrOff, csrE, gb, out_n);
        k_colstat1<<<64,256,0,stream>>>(out_n, part1, part2);
        k_colstat2<<<2,256,0,stream>>>(part1, part2, nw, ns, mu, gsc);
        k_gnapply<<<(NNODE*FDIM+255)/256,256,0,stream>>>(out_n, mu, gsc, ns, nb_, Xout);
    }

    // ---- final heads (only rows 0..7 matter) ----
    k_final<<<NBAGS,HIDN,0,stream>>>(x1buf, x2buf, f1W, f1b, f2W, f2b, clW, clb, out);
}

// Round 18
// 1494.012 us; speedup vs baseline: 1.2726x; 1.0051x over previous
//
#include <hip/hip_runtime.h>
#include <math.h>
#include <limits.h>

#define FDIM 512
#define HIDN 256
#define NBAGS 8
#define NINST 16384
#define NNODE 8200
#define NEDGE 32800
#define BFSPLIT 16
#define SPLITW 513
#define MCHUNK 128

typedef __attribute__((ext_vector_type(8))) short short8v;   // 8 bf16 (4 VGPR)
typedef __attribute__((ext_vector_type(4))) float f32x4v;    // MFMA C/D frag

__device__ __forceinline__ float lrelu(float v, float s){ return v >= 0.f ? v : v*s; }

// sorted-4 insert with jax.lax.top_k tie semantics (lower index wins ties)
__device__ __forceinline__ void ins4(float v, int id, float* tv, int* ti){
    if ((v > tv[3]) || (v == tv[3] && id < ti[3])){
        tv[3]=v; ti[3]=id;
#pragma unroll
        for (int q=3;q>0;--q){
            bool sw = (tv[q] > tv[q-1]) || (tv[q]==tv[q-1] && ti[q]<ti[q-1]);
            if (sw){ float f=tv[q]; tv[q]=tv[q-1]; tv[q-1]=f; int d=ti[q]; ti[q]=ti[q-1]; ti[q-1]=d; }
        }
    }
}

__device__ __forceinline__ void ins8(float v, int id, float* tv, int* ti){
    if ((v > tv[7]) || (v == tv[7] && id < ti[7])){
        tv[7]=v; ti[7]=id;
#pragma unroll
        for (int q=7;q>0;--q){
            bool sw = (tv[q] > tv[q-1]) || (tv[q]==tv[q-1] && ti[q]<ti[q-1]);
            if (sw){ float f=tv[q]; tv[q]=tv[q-1]; tv[q-1]=f; int d=ti[q]; ti[q]=ti[q-1]; ti[q-1]=d; }
        }
    }
}

__device__ __forceinline__ unsigned short f2bf(float f){
    unsigned u = __float_as_uint(f);
    unsigned r = u + 0x7FFFu + ((u >> 16) & 1u);   // round-to-nearest-even
    return (unsigned short)(r >> 16);
}
__device__ __forceinline__ float bf2f(unsigned short h){
    return __uint_as_float((unsigned)h << 16);
}

// ---------------------------------------------------------------------------
// 512x512 weight split: WThi/WTlo[n][k] = bf16 hi/lo of W[k][n] (transposed)
// ---------------------------------------------------------------------------
__global__ void k_wsplit(const float* __restrict__ W,
        unsigned short* __restrict__ WThi, unsigned short* __restrict__ WTlo){
    int i = blockIdx.x*256 + threadIdx.x;          // i over 512*512
    int k = i >> 9, n = i & 511;
    float w = W[i];                                 // W[k][n]
    unsigned short hi = f2bf(w);
    unsigned short lo = f2bf(w - bf2f(hi));
    WThi[(size_t)n*512 + k] = hi;
    WTlo[(size_t)n*512 + k] = lo;
}

// ---------------------------------------------------------------------------
// scores via bf16x3 split MFMA (round-15 validated: LDS + register prefetch)
// + XCD-aware block swizzle: 1D grid 4096 = 1024 row-blocks x 4 col-splits;
// nid = (lid&7)*512 + (lid>>3) gives each XCD a contiguous run of row-blocks
// with ALL 4 col-splits -> A-row re-reads hit the local L2 instead of HBM.
// Pure index bijection; identical arithmetic per tile -> scoresP bit-exact.
// ---------------------------------------------------------------------------
__global__ __launch_bounds__(256) void k_scores(const float* __restrict__ X,
        const unsigned short* __restrict__ WThi, const unsigned short* __restrict__ WTlo,
        const float* __restrict__ b1, const float* __restrict__ v2,
        float* __restrict__ scoresP)
{
    __shared__ unsigned short Ahi[128][40];
    __shared__ unsigned short Alo[128][40];
    __shared__ unsigned short Bhi[128][40];
    __shared__ unsigned short Blo[128][40];
    int t = threadIdx.x;
    int wv = t >> 6, lane = t & 63;
    int lcol = lane & 15, lk = lane >> 4;
    int lid = blockIdx.x;                       // 0..4095
    int nid = (lid & 7) * 512 + (lid >> 3);     // XCD-chunked bijection
    int split = nid & 3;
    size_t mb = (size_t)(nid >> 2) * 128;
    int nb = split * 128;

    f32x4v acc[2][8];
#pragma unroll
    for (int rf=0;rf<2;rf++)
#pragma unroll
        for (int cf=0;cf<8;cf++) acc[rf][cf] = (f32x4v){0.f,0.f,0.f,0.f};

    int segA = t & 7, rowA = t >> 3;
    int colB = t >> 2, partB = t & 3;

    float4 pa[4];
    short8v pwh[2], pwl[2];
#pragma unroll
    for (int q=0;q<4;q++)
        pa[q] = *(const float4*)(X + (mb + rowA + q*32)*512 + segA*4);
#pragma unroll
    for (int q=0;q<2;q++){
        int col = colB + q*64;
        pwh[q] = *(const short8v*)(WThi + (size_t)(nb+col)*512 + partB*8);
        pwl[q] = *(const short8v*)(WTlo + (size_t)(nb+col)*512 + partB*8);
    }

    for (int kc = 0; kc < 512; kc += 32){
        __syncthreads();
#pragma unroll
        for (int q=0;q<4;q++){
            float4 v = pa[q];
            ushort4 h, l;
            h.x=f2bf(v.x); h.y=f2bf(v.y); h.z=f2bf(v.z); h.w=f2bf(v.w);
            l.x=f2bf(v.x-bf2f(h.x)); l.y=f2bf(v.y-bf2f(h.y));
            l.z=f2bf(v.z-bf2f(h.z)); l.w=f2bf(v.w-bf2f(h.w));
            *(ushort4*)&Ahi[rowA + q*32][segA*4] = h;
            *(ushort4*)&Alo[rowA + q*32][segA*4] = l;
        }
#pragma unroll
        for (int q=0;q<2;q++){
            *(short8v*)&Bhi[colB + q*64][partB*8] = pwh[q];
            *(short8v*)&Blo[colB + q*64][partB*8] = pwl[q];
        }
        __syncthreads();
        if (kc + 32 < 512){
            int kn = kc + 32;
#pragma unroll
            for (int q=0;q<4;q++)
                pa[q] = *(const float4*)(X + (mb + rowA + q*32)*512 + kn + segA*4);
#pragma unroll
            for (int q=0;q<2;q++){
                int col = colB + q*64;
                pwh[q] = *(const short8v*)(WThi + (size_t)(nb+col)*512 + kn + partB*8);
                pwl[q] = *(const short8v*)(WTlo + (size_t)(nb+col)*512 + kn + partB*8);
            }
        }
        int r0 = wv*32;
        short8v ah0 = *(const short8v*)&Ahi[r0      + lcol][lk*8];
        short8v al0 = *(const short8v*)&Alo[r0      + lcol][lk*8];
        short8v ah1 = *(const short8v*)&Ahi[r0 + 16 + lcol][lk*8];
        short8v al1 = *(const short8v*)&Alo[r0 + 16 + lcol][lk*8];
#pragma unroll
        for (int cf=0; cf<8; cf++){
            short8v bh = *(const short8v*)&Bhi[cf*16 + lcol][lk*8];
            short8v bl = *(const short8v*)&Blo[cf*16 + lcol][lk*8];
            acc[0][cf] = __builtin_amdgcn_mfma_f32_16x16x32_bf16(ah0, bh, acc[0][cf], 0,0,0);
            acc[0][cf] = __builtin_amdgcn_mfma_f32_16x16x32_bf16(ah0, bl, acc[0][cf], 0,0,0);
            acc[0][cf] = __builtin_amdgcn_mfma_f32_16x16x32_bf16(al0, bh, acc[0][cf], 0,0,0);
            acc[1][cf] = __builtin_amdgcn_mfma_f32_16x16x32_bf16(ah1, bh, acc[1][cf], 0,0,0);
            acc[1][cf] = __builtin_amdgcn_mfma_f32_16x16x32_bf16(ah1, bl, acc[1][cf], 0,0,0);
            acc[1][cf] = __builtin_amdgcn_mfma_f32_16x16x32_bf16(al1, bh, acc[1][cf], 0,0,0);
        }
    }
    float rowsum[2][4];
#pragma unroll
    for (int rf=0;rf<2;rf++)
#pragma unroll
        for (int r=0;r<4;r++) rowsum[rf][r]=0.f;
#pragma unroll
    for (int rf=0; rf<2; rf++)
#pragma unroll
        for (int cf=0; cf<8; cf++){
            int gc = nb + cf*16 + lcol;
            float bb = b1[gc], vv = v2[gc];
#pragma unroll
            for (int r=0;r<4;r++){
                float h = acc[rf][cf][r] + bb;
                h = h > 0.f ? h : 0.f;
                rowsum[rf][r] = fmaf(h, vv, rowsum[rf][r]);
            }
        }
#pragma unroll
    for (int mask=1; mask<16; mask<<=1)
#pragma unroll
        for (int rf=0;rf<2;rf++)
#pragma unroll
            for (int r=0;r<4;r++)
                rowsum[rf][r] += __shfl_xor(rowsum[rf][r], mask);
    if (lcol == 0){
#pragma unroll
        for (int rf=0;rf<2;rf++)
#pragma unroll
            for (int r=0;r<4;r++){
                size_t grow = mb + wv*32 + rf*16 + lk*4 + r;
                scoresP[(size_t)split*(NBAGS*NINST) + grow] = rowsum[rf][r];
            }
    }
}

// ---------------------------------------------------------------------------
// generic bf16x3 MFMA GEMM (round-15 validated: LDS + register prefetch)
// ---------------------------------------------------------------------------
__global__ __launch_bounds__(256) void k_gemm3(const float* __restrict__ X,
        const unsigned short* __restrict__ WThi, const unsigned short* __restrict__ WTlo,
        const float* __restrict__ bias, float* __restrict__ C,
        int M, int N, int K, float slope)
{
    __shared__ unsigned short Ahi[128][40];
    __shared__ unsigned short Alo[128][40];
    __shared__ unsigned short Bhi[128][40];
    __shared__ unsigned short Blo[128][40];
    int t = threadIdx.x;
    int wv = t >> 6, lane = t & 63;
    int lcol = lane & 15, lk = lane >> 4;
    int mb = blockIdx.y * 128;
    int nb = blockIdx.x * 128;

    f32x4v acc[2][8];
#pragma unroll
    for (int rf=0;rf<2;rf++)
#pragma unroll
        for (int cf=0;cf<8;cf++) acc[rf][cf] = (f32x4v){0.f,0.f,0.f,0.f};

    int segA = t & 7, rowA = t >> 3;
    int colB = t >> 2, partB = t & 3;
    int grA[4];
#pragma unroll
    for (int q=0;q<4;q++){
        int gr = mb + rowA + q*32; if (gr >= M) gr = M-1;
        grA[q] = gr;
    }

    float4 pa[4];
    short8v pwh[2], pwl[2];
#pragma unroll
    for (int q=0;q<4;q++)
        pa[q] = *(const float4*)(X + (size_t)grA[q]*K + segA*4);
#pragma unroll
    for (int q=0;q<2;q++){
        int col = colB + q*64;
        pwh[q] = *(const short8v*)(WThi + (size_t)(nb+col)*K + partB*8);
        pwl[q] = *(const short8v*)(WTlo + (size_t)(nb+col)*K + partB*8);
    }

    for (int kc = 0; kc < K; kc += 32){
        __syncthreads();
#pragma unroll
        for (int q=0;q<4;q++){
            float4 v = pa[q];
            ushort4 h, l;
            h.x=f2bf(v.x); h.y=f2bf(v.y); h.z=f2bf(v.z); h.w=f2bf(v.w);
            l.x=f2bf(v.x-bf2f(h.x)); l.y=f2bf(v.y-bf2f(h.y));
            l.z=f2bf(v.z-bf2f(h.z)); l.w=f2bf(v.w-bf2f(h.w));
            *(ushort4*)&Ahi[rowA + q*32][segA*4] = h;
            *(ushort4*)&Alo[rowA + q*32][segA*4] = l;
        }
#pragma unroll
        for (int q=0;q<2;q++){
            *(short8v*)&Bhi[colB + q*64][partB*8] = pwh[q];
            *(short8v*)&Blo[colB + q*64][partB*8] = pwl[q];
        }
        __syncthreads();
        if (kc + 32 < K){
            int kn = kc + 32;
#pragma unroll
            for (int q=0;q<4;q++)
                pa[q] = *(const float4*)(X + (size_t)grA[q]*K + kn + segA*4);
#pragma unroll
            for (int q=0;q<2;q++){
                int col = colB + q*64;
                pwh[q] = *(const short8v*)(WThi + (size_t)(nb+col)*K + kn + partB*8);
                pwl[q] = *(const short8v*)(WTlo + (size_t)(nb+col)*K + kn + partB*8);
            }
        }
        int r0 = wv*32;
        short8v ah0 = *(const short8v*)&Ahi[r0      + lcol][lk*8];
        short8v al0 = *(const short8v*)&Alo[r0      + lcol][lk*8];
        short8v ah1 = *(const short8v*)&Ahi[r0 + 16 + lcol][lk*8];
        short8v al1 = *(const short8v*)&Alo[r0 + 16 + lcol][lk*8];
#pragma unroll
        for (int cf=0; cf<8; cf++){
            short8v bh = *(const short8v*)&Bhi[cf*16 + lcol][lk*8];
            short8v bl = *(const short8v*)&Blo[cf*16 + lcol][lk*8];
            acc[0][cf] = __builtin_amdgcn_mfma_f32_16x16x32_bf16(ah0, bh, acc[0][cf], 0,0,0);
            acc[0][cf] = __builtin_amdgcn_mfma_f32_16x16x32_bf16(ah0, bl, acc[0][cf], 0,0,0);
            acc[0][cf] = __builtin_amdgcn_mfma_f32_16x16x32_bf16(al0, bh, acc[0][cf], 0,0,0);
            acc[1][cf] = __builtin_amdgcn_mfma_f32_16x16x32_bf16(ah1, bh, acc[1][cf], 0,0,0);
            acc[1][cf] = __builtin_amdgcn_mfma_f32_16x16x32_bf16(ah1, bl, acc[1][cf], 0,0,0);
            acc[1][cf] = __builtin_amdgcn_mfma_f32_16x16x32_bf16(al1, bh, acc[1][cf], 0,0,0);
        }
    }
#pragma unroll
    for (int rf=0; rf<2; rf++)
#pragma unroll
        for (int cf=0; cf<8; cf++){
            int gc = nb + cf*16 + lcol;
            float bb = bias ? bias[gc] : 0.f;
#pragma unroll
            for (int r=0;r<4;r++){
                int grow = mb + wv*32 + rf*16 + lk*4 + r;
                if (grow < M){
                    float v = acc[rf][cf][r] + bb;
                    C[(size_t)grow*N + gc] = lrelu(v, slope);
                }
            }
        }
}

__global__ void k_scred(const float* __restrict__ sp, float* __restrict__ s){
    int r = blockIdx.x*256+threadIdx.x;
    if (r < NBAGS*NINST)
        s[r] = sp[r] + sp[NBAGS*NINST + r] + sp[2*NBAGS*NINST + r] + sp[3*NBAGS*NINST + r];
}

// softmax over 16384 per bag, in place
__global__ __launch_bounds__(256) void k_softmax(float* __restrict__ s0){
    int b = blockIdx.x; float* s = s0 + (size_t)b*NINST;
    __shared__ float red[256];
    int t = threadIdx.x;
    float m = -INFINITY;
    for (int i=t;i<NINST;i+=256) m = fmaxf(m, s[i]);
    red[t]=m; __syncthreads();
    for (int st=128; st>0; st>>=1){ if(t<st) red[t]=fmaxf(red[t],red[t+st]); __syncthreads(); }
    m = red[0]; __syncthreads();
    float sum=0.f;
    for (int i=t;i<NINST;i+=256) sum += __expf(s[i]-m);
    red[t]=sum; __syncthreads();
    for (int st=128; st>0; st>>=1){ if(t<st) red[t]+=red[t+st]; __syncthreads(); }
    float inv = 1.f/red[0];
    for (int i=t;i<NINST;i+=256) s[i] = __expf(s[i]-m)*inv;
}

// M partials: MP[(chunk*8+b)*512+d]; 128 chunks x 8 bags = 1024 blocks
__global__ __launch_bounds__(256) void k_M(const float* __restrict__ x,
        const float* __restrict__ A, float* __restrict__ MP){
    int b = blockIdx.y; int chunk = blockIdx.x;
    int n0 = chunk*(NINST/MCHUNK);
    __shared__ float As[NINST/MCHUNK];
    int t=threadIdx.x;
    if (t < NINST/MCHUNK) As[t] = A[(size_t)b*NINST+n0+t];
    __syncthreads();
    float a0=0.f, a1=0.f;
    const float* xb = x + ((size_t)b*NINST + n0)*FDIM;
    for (int n=0;n<NINST/MCHUNK;n++){
        float w = As[n];
        a0 = fmaf(w, xb[(size_t)n*FDIM + t],       a0);
        a1 = fmaf(w, xb[(size_t)n*FDIM + t + 256], a1);
    }
    MP[((size_t)chunk*NBAGS + b)*FDIM + t]       = a0;
    MP[((size_t)chunk*NBAGS + b)*FDIM + t + 256] = a1;
}

__global__ void k_Mred(const float* __restrict__ mp, float* __restrict__ M_){
    int b = blockIdx.x; int d = threadIdx.x; // 512 threads
    float s=0.f;
    for (int c=0;c<MCHUNK;c++) s += mp[((size_t)c*NBAGS+b)*FDIM + d];
    M_[b*FDIM+d]=s;
}

__global__ void k_logits_mlp(const float* __restrict__ M_, const float* __restrict__ cW,
        const float* __restrict__ cb, float* __restrict__ outp){
    int t = threadIdx.x;
    if (t < 16){
        int r=t>>1, c=t&1;
        float s=cb[c];
        for (int k=0;k<FDIM;k++) s = fmaf(M_[r*FDIM+k], cW[k*2+c], s);
        outp[r*2+c] = s;
    }
}

__global__ void k_xc(const float* __restrict__ M_, const float* __restrict__ reh, float* __restrict__ xc){
    size_t i = (size_t)blockIdx.x*256 + threadIdx.x;
    if (i >= (size_t)NNODE*FDIM) return;
    xc[i] = (i < (size_t)NBAGS*FDIM) ? M_[i] : reh[i - (size_t)NBAGS*FDIM];
}

// ---------------------------------------------------------------------------
// fp32 GEMM (projector only — keeps xg bit-exact for the exact kNN rescore)
// ---------------------------------------------------------------------------
__global__ __launch_bounds__(256) void k_gemm(const float* __restrict__ X,
        const float* __restrict__ W, const float* __restrict__ bias,
        float* __restrict__ C, unsigned short* __restrict__ Cbf,
        int M, int N, int K, float slope)
{
    __shared__ float As[32][68];
    __shared__ float Ws[32][128];
    int t = threadIdx.x; int tx = t & 15, ty = t >> 4;
    int mb = blockIdx.y * 64, nb = blockIdx.x * 128;
    float acc[4][8];
#pragma unroll
    for (int i=0;i<4;i++)
#pragma unroll
        for (int j=0;j<8;j++) acc[i][j]=0.f;

    int kq=(t&7)*4, m0=t>>3;
    int n4=(t&31)*4, k0=t>>5;
    for (int kc=0;kc<K;kc+=32){
#pragma unroll
        for (int mm=0;mm<2;mm++){
            int m = m0 + mm*32;
            int gr = mb + m; if (gr >= M) gr = M-1;
            float4 v = *(const float4*)(X + (size_t)gr*K + kc + kq);
            As[kq+0][m]=v.x; As[kq+1][m]=v.y; As[kq+2][m]=v.z; As[kq+3][m]=v.w;
        }
#pragma unroll
        for (int kk=0;kk<4;kk++){
            float4 v = *(const float4*)(W + (size_t)(kc+k0+kk*8)*N + nb + n4);
            *(float4*)&Ws[k0+kk*8][n4] = v;
        }
        __syncthreads();
#pragma unroll 4
        for (int k=0;k<32;k++){
            float4 a = *(const float4*)&As[k][ty*4];
            float4 b0 = *(const float4*)&Ws[k][tx*4];
            float4 b1 = *(const float4*)&Ws[k][64+tx*4];
            float av[4]={a.x,a.y,a.z,a.w};
            float bv[8]={b0.x,b0.y,b0.z,b0.w,b1.x,b1.y,b1.z,b1.w};
#pragma unroll
            for (int i=0;i<4;i++)
#pragma unroll
                for (int j=0;j<8;j++)
                    acc[i][j] = fmaf(av[i], bv[j], acc[i][j]);
        }
        __syncthreads();
    }
#pragma unroll
    for (int i=0;i<4;i++){
        int gr = mb + ty*4 + i;
        if (gr >= M) continue;
        float o[8];
#pragma unroll
        for (int j=0;j<8;j++){
            int gc = (j<4) ? (nb + tx*4 + j) : (nb + 64 + tx*4 + (j-4));
            float v = acc[i][j] + (bias ? bias[gc] : 0.f);
            o[j] = lrelu(v, slope);
        }
        float4 o0 = make_float4(o[0],o[1],o[2],o[3]);
        float4 o1 = make_float4(o[4],o[5],o[6],o[7]);
        *(float4*)(C + (size_t)gr*N + nb + tx*4)      = o0;
        *(float4*)(C + (size_t)gr*N + nb + 64 + tx*4) = o1;
        if (Cbf){
            ushort4 h0, h1;
            h0.x=f2bf(o[0]); h0.y=f2bf(o[1]); h0.z=f2bf(o[2]); h0.w=f2bf(o[3]);
            h1.x=f2bf(o[4]); h1.y=f2bf(o[5]); h1.z=f2bf(o[6]); h1.w=f2bf(o[7]);
            *(ushort4*)(Cbf + (size_t)gr*N + nb + tx*4)      = h0;
            *(ushort4*)(Cbf + (size_t)gr*N + nb + 64 + tx*4) = h1;
        }
    }
}

// row dot: mode 0: out[r] = X[r]·v ; mode 1: out[r] = 1/(sqrt(X[r]·X[r])+1e-12)
__global__ void k_rowdot(const float* __restrict__ X, const float* __restrict__ v,
        float* __restrict__ out, int K, int mode){
    int r = blockIdx.x; int t = threadIdx.x;
    const float* xr = X + (size_t)r*K;
    float s = 0.f;
    if (mode==1){ for (int k=t;k<K;k+=64){ float x_=xr[k]; s=fmaf(x_,x_,s);} }
    else        { for (int k=t;k<K;k+=64) s=fmaf(xr[k],v[k],s); }
    for (int off=32;off;off>>=1) s += __shfl_down(s, off);
    if (t==0) out[r] = (mode==1)? 1.f/(sqrtf(s)+1e-12f) : s;
}

// w2[k] = sum_j W[k][j]*att2[j]
__global__ void k_watt(const float* __restrict__ W, const float* __restrict__ att2, float* __restrict__ w2){
    int k = blockIdx.x; int t=threadIdx.x;
    float s=0.f;
    for (int j=t;j<FDIM;j+=64) s=fmaf(W[(size_t)k*FDIM+j], att2[j], s);
    for (int off=32;off;off>>=1) s += __shfl_down(s, off);
    if (t==0) w2[k]=s;
}

// ---------------------------------------------------------------------------
// bf16 MFMA prefilter (round-15/17 validated verbatim)
// ---------------------------------------------------------------------------
__global__ __launch_bounds__(256) void k_simbf(const unsigned short* __restrict__ xgh,
        const float* __restrict__ rn, float* __restrict__ candV, int* __restrict__ candI)
{
    __shared__ unsigned short Bs[16][520];
    int t = threadIdx.x;
    int wv = t >> 6, lane = t & 63;
    int lcol = lane & 15, lk = lane >> 4;
    int split = blockIdx.x;
    int r0 = blockIdx.y * 64 + wv * 16;

    short8v aF[16];
    {
        int arow = r0 + lcol; if (arow >= NNODE) arow = NNODE - 1;
        const unsigned short* ap = xgh + (size_t)arow * FDIM + lk * 8;
#pragma unroll
        for (int s = 0; s < 16; s++)
            aF[s] = *(const short8v*)(ap + s * 32);
    }

    int c0 = split * SPLITW;
    int cend = c0 + SPLITW; if (cend > NNODE) cend = NNODE;

    float tv[4][4]; int ti[4][4];
#pragma unroll
    for (int i=0;i<4;i++)
#pragma unroll
        for (int q=0;q<4;q++){ tv[i][q]=-INFINITY; ti[i][q]=INT_MAX; }

    int rho = t >> 4, seg = t & 15;

    short8v pb[4];
    {
        int gc = c0 + rho; if (gc >= cend) gc = cend - 1;
        const unsigned short* bp = xgh + (size_t)gc * FDIM;
#pragma unroll
        for (int p = 0; p < 4; p++)
            pb[p] = *(const short8v*)(bp + seg*8 + p*128);
    }

    for (int cc = c0; cc < cend; cc += 16){
        __syncthreads();
#pragma unroll
        for (int p = 0; p < 4; p++)
            *(short8v*)&Bs[rho][seg*8 + p*128] = pb[p];
        __syncthreads();
        if (cc + 16 < cend){
            int gc = cc + 16 + rho; if (gc >= cend) gc = cend - 1;
            const unsigned short* bp = xgh + (size_t)gc * FDIM;
#pragma unroll
            for (int p = 0; p < 4; p++)
                pb[p] = *(const short8v*)(bp + seg*8 + p*128);
        }

        f32x4v acc0 = {0.f,0.f,0.f,0.f};
        f32x4v acc1 = {0.f,0.f,0.f,0.f};
#pragma unroll
        for (int s = 0; s < 8; s++){
            short8v b0 = *(const short8v*)&Bs[lcol][lk*8 + s*32];
            short8v b1 = *(const short8v*)&Bs[lcol][lk*8 + (s+8)*32];
            acc0 = __builtin_amdgcn_mfma_f32_16x16x32_bf16(aF[s],   b0, acc0, 0, 0, 0);
            acc1 = __builtin_amdgcn_mfma_f32_16x16x32_bf16(aF[s+8], b1, acc1, 0, 0, 0);
        }
        int gcol = cc + lcol;
        bool valid = gcol < cend;
        float rnc = valid ? rn[gcol] : 0.f;
#pragma unroll
        for (int i = 0; i < 4; i++){
            float v = valid ? (acc0[i] + acc1[i]) * rnc : -INFINITY;
            ins4(v, gcol, tv[i], ti[i]);
        }
    }

    float mv[4][8]; int mi[4][8];
#pragma unroll
    for (int i=0;i<4;i++){
#pragma unroll
        for (int q=0;q<4;q++){ mv[i][q]=tv[i][q]; mi[i][q]=ti[i][q]; }
#pragma unroll
        for (int q=4;q<8;q++){ mv[i][q]=-INFINITY; mi[i][q]=INT_MAX; }
    }
#pragma unroll
    for (int mask=1; mask<16; mask<<=1){
        float ov[4][8]; int oi[4][8];
#pragma unroll
        for (int i=0;i<4;i++)
#pragma unroll
            for (int q=0;q<8;q++){
                ov[i][q] = __shfl_xor(mv[i][q], mask);
                oi[i][q] = __shfl_xor(mi[i][q], mask);
            }
#pragma unroll
        for (int i=0;i<4;i++)
#pragma unroll
            for (int q=0;q<8;q++)
                ins8(ov[i][q], oi[i][q], mv[i], mi[i]);
    }
    if (lcol == 0){
#pragma unroll
        for (int i=0;i<4;i++){
            int grow = r0 + lk*4 + i;
            if (grow < NNODE){
#pragma unroll
                for (int q=0;q<8;q++){
                    candV[((size_t)grow*BFSPLIT + split)*8 + q] = mv[i][q];
                    candI[((size_t)grow*BFSPLIT + split)*8 + q] = mi[i][q];
                }
            }
        }
    }
}

// ---------------------------------------------------------------------------
// exact rescore (round-17 validated: both halves in one grid, blockIdx.y=half)
// ---------------------------------------------------------------------------
__global__ __launch_bounds__(256) void k_rescore(const float* __restrict__ xg,
        const float* __restrict__ rn, const float* __restrict__ candV,
        const int* __restrict__ candI,
        float* __restrict__ htV, int* __restrict__ htI)
{
    __shared__ float Xr[4][512];        // 8 KB
    __shared__ float Cs[256][17];       // 17408 B
    __shared__ int   CrowS[256];        // 1 KB
    int t = threadIdx.x;
    int wv = t >> 6, lane = t & 63;
    int half = blockIdx.y;
    int r0 = blockIdx.x * 4;
    int r  = r0 + wv;
    int cid = candI[(size_t)r*128 + half*64 + lane];
    float pv = candV[(size_t)r*128 + half*64 + lane];
    bool ok = (pv != -INFINITY) && (cid >= 0) && (cid < NNODE);
    int crow = ok ? cid : 0;
    CrowS[t] = crow;
    {
        int rr = t >> 6; int c = t & 63;
        const float* xp = xg + (size_t)(r0+rr)*FDIM;
        *(float4*)&Xr[rr][c*4]       = *(const float4*)(xp + c*4);
        *(float4*)&Xr[rr][256 + c*4] = *(const float4*)(xp + 256 + c*4);
    }
    float dot = 0.f;
    for (int kc = 0; kc < 512; kc += 16){
        __syncthreads();
#pragma unroll
        for (int p = 0; p < 4; p++){
            int slot = p*64 + (t >> 2);
            int f = t & 3;
            float4 v = *(const float4*)(xg + (size_t)CrowS[slot]*FDIM + kc + f*4);
            float* dst = &Cs[slot][f*4];
            dst[0]=v.x; dst[1]=v.y; dst[2]=v.z; dst[3]=v.w;
        }
        __syncthreads();
#pragma unroll
        for (int k2 = 0; k2 < 16; k2++)
            dot = fmaf(Xr[wv][kc + k2], Cs[t][k2], dot);
    }
    float v = ok ? (dot * rn[r]) * rn[crow] : -INFINITY;
    int id = ok ? cid : INT_MAX;
    float tvv[4]={-INFINITY,-INFINITY,-INFINITY,-INFINITY};
    int tii[4]={INT_MAX,INT_MAX,INT_MAX,INT_MAX};
    ins4(v, id, tvv, tii);
#pragma unroll
    for (int mask=1; mask<64; mask<<=1){
        float ov[4]; int oi[4];
#pragma unroll
        for (int s=0;s<4;s++){ ov[s]=__shfl_xor(tvv[s],mask); oi[s]=__shfl_xor(tii[s],mask); }
#pragma unroll
        for (int s=0;s<4;s++) ins4(ov[s], oi[s], tvv, tii);
    }
    if (lane == 0){
#pragma unroll
        for (int s=0;s<4;s++){ htV[r*8 + half*4 + s] = tvv[s]; htI[r*8 + half*4 + s] = tii[s]; }
    }
}

// merge the two exact half-top-4 lists (disjoint col ranges) -> global top-4
__global__ void k_hmerge(const float* __restrict__ htV, const int* __restrict__ htI,
        int* __restrict__ nbr){
    int r = blockIdx.x*256+threadIdx.x; if (r>=NNODE) return;
    float tv[4]={-INFINITY,-INFINITY,-INFINITY,-INFINITY};
    int ti[4]={INT_MAX,INT_MAX,INT_MAX,INT_MAX};
#pragma unroll
    for (int q=0;q<8;q++) ins4(htV[r*8+q], htI[r*8+q], tv, ti);
#pragma unroll
    for (int s=0;s<4;s++) nbr[r*4+s] = ti[s];
}

__global__ void k_eattr(const float* __restrict__ xg, const int* __restrict__ nbr, float* __restrict__ ea){
    int j = blockIdx.x; int t = threadIdx.x;
    int n0=nbr[j*4], n1=nbr[j*4+1], n2=nbr[j*4+2], n3=nbr[j*4+3];
    for (int d=t; d<FDIM; d+=256){
        float s = xg[(size_t)n0*FDIM+d]+xg[(size_t)n1*FDIM+d]+xg[(size_t)n2*FDIM+d]+xg[(size_t)n3*FDIM+d];
        ea[(size_t)j*FDIM+d] = 0.25f*s;
    }
}

__global__ void k_count(const int* __restrict__ nbr, int* __restrict__ counts){
    int e = blockIdx.x*256+threadIdx.x; if(e<NEDGE) atomicAdd(&counts[nbr[e]],1);
}

__global__ void k_scan(const int* __restrict__ counts, int* __restrict__ csrOff){
    __shared__ int part[257];
    int t=threadIdx.x;
    int start = t*33; int s=0;
    for (int i=0;i<33;i++){ int idx=start+i; if(idx<NNODE) s += counts[idx]; }
    part[t+1]=s; if(t==0) part[0]=0;
    __syncthreads();
    if (t==0){ for (int i=1;i<=256;i++) part[i]+=part[i-1]; }
    __syncthreads();
    int run = part[t];
    for (int i=0;i<33;i++){ int idx=start+i; if(idx<NNODE){ csrOff[idx]=run; run+=counts[idx]; } }
    if (t==255) csrOff[NNODE]=run;
}

__global__ void k_fill(const int* __restrict__ nbr, const int* __restrict__ csrOff,
        int* __restrict__ fillPos, int* __restrict__ csrE){
    int e = blockIdx.x*256+threadIdx.x; if(e>=NEDGE) return;
    int i = nbr[e];
    int p = atomicAdd(&fillPos[i],1);
    csrE[csrOff[i]+p] = e;
}

__global__ void k_alpha(const int* __restrict__ nbr, const float* __restrict__ ps,
        const float* __restrict__ pe, float* __restrict__ alphan){
    int e = blockIdx.x*256+threadIdx.x; if(e>=NEDGE) return;
    float a = ps[nbr[e]] + pe[e>>2];
    alphan[e] = a>=0.f? a : 0.2f*a;
}

__global__ void k_esm(const int* __restrict__ csrOff, const int* __restrict__ csrE,
        float* __restrict__ alphan){
    int i = blockIdx.x*256+threadIdx.x; if(i>=NNODE) return;
    int s0=csrOff[i], s1=csrOff[i+1];
    if (s1==s0) return;
    float m=-INFINITY;
    for (int s=s0;s<s1;s++) m = fmaxf(m, alphan[csrE[s]]);
    float Z=0.f;
    for (int s=s0;s<s1;s++) Z += __expf(alphan[csrE[s]]-m);
    float inv = 1.f/Z;
    for (int s=s0;s<s1;s++){ int e=csrE[s]; alphan[e] = __expf(alphan[e]-m)*inv; }
}

__global__ void k_oute(const float* __restrict__ xs, const float* __restrict__ alphan,
        const int* __restrict__ nbr, float* __restrict__ out_e){
    int j = blockIdx.x; int t=threadIdx.x;
    __shared__ float a[4]; __shared__ int sidx[4];
    if (t<4){ a[t]=alphan[j*4+t]; sidx[t]=nbr[j*4+t]; }
    __syncthreads();
    for (int d=t; d<FDIM; d+=256){
        float v = a[0]*xs[(size_t)sidx[0]*FDIM+d] + a[1]*xs[(size_t)sidx[1]*FDIM+d]
                + a[2]*xs[(size_t)sidx[2]*FDIM+d] + a[3]*xs[(size_t)sidx[3]*FDIM+d];
        out_e[(size_t)j*FDIM+d] = 0.25f*v;
    }
}

__global__ void k_outn(const float* __restrict__ out_e, const float* __restrict__ alphan,
        const int* __restrict__ csrOff, const int* __restrict__ csrE,
        const float* __restrict__ bias, float* __restrict__ out_n){
    int i = blockIdx.x; int t=threadIdx.x;
    int s0=csrOff[i], s1=csrOff[i+1];
    float Dinv = (s1>s0)? 1.f/(float)(s1-s0) : 0.f;
    for (int d=t; d<FDIM; d+=256){
        float accv=0.f;
        for (int s=s0;s<s1;s++){
            int e=csrE[s];
            accv = fmaf(alphan[e], out_e[(size_t)(e>>2)*FDIM+d], accv);
        }
        out_n[(size_t)i*FDIM+d] = bias[d] + Dinv*accv;
    }
}

__global__ void k_colstat1(const float* __restrict__ Xn, float* __restrict__ p1, float* __restrict__ p2){
    int b = blockIdx.x; int t=threadIdx.x;
    float s0=0,q0=0,s1=0,q1=0;
    for (int r=b; r<NNODE; r+=64){
        float v0 = Xn[(size_t)r*FDIM + t];
        float v1 = Xn[(size_t)r*FDIM + t + 256];
        s0+=v0; q0=fmaf(v0,v0,q0); s1+=v1; q1=fmaf(v1,v1,q1);
    }
    p1[b*FDIM+t]=s0; p1[b*FDIM+t+256]=s1;
    p2[b*FDIM+t]=q0; p2[b*FDIM+t+256]=q1;
}

__global__ void k_colstat2(const float* __restrict__ p1, const float* __restrict__ p2,
        const float* __restrict__ w, const float* __restrict__ sc,
        float* __restrict__ mu, float* __restrict__ g){
    int d = threadIdx.x + blockIdx.x*256; if(d>=FDIM) return;
    float s=0,q=0;
    for (int bb=0;bb<64;bb++){ s+=p1[bb*FDIM+d]; q+=p2[bb*FDIM+d]; }
    float m = s/(float)NNODE;
    float ms = m*sc[d];
    float var = q/(float)NNODE - 2.f*ms*m + ms*ms;
    mu[d]=m;
    g[d] = w[d]*rsqrtf(var+1e-5f);
}

__global__ void k_gnapply(const float* __restrict__ Xin, const float* __restrict__ mu,
        const float* __restrict__ g, const float* __restrict__ sc,
        const float* __restrict__ bb, float* __restrict__ Xout){
    size_t i = (size_t)blockIdx.x*256+threadIdx.x;
    if (i >= (size_t)NNODE*FDIM) return;
    int d = (int)(i & 511);
    float o = Xin[i] - mu[d]*sc[d];
    Xout[i] = lrelu(g[d]*o + bb[d], 0.01f);
}

__global__ void k_final(const float* __restrict__ x1, const float* __restrict__ x2,
        const float* __restrict__ f1W, const float* __restrict__ f1b,
        const float* __restrict__ f2W, const float* __restrict__ f2b,
        const float* __restrict__ clW, const float* __restrict__ clb,
        float* __restrict__ outp){
    int r = blockIdx.x;
    int h = threadIdx.x;
    __shared__ float o8[HIDN];
    float s1=f1b[h], s2=f2b[h];
    for (int k=0;k<FDIM;k++){
        s1 = fmaf(x1[(size_t)r*FDIM+k], f1W[(size_t)k*HIDN+h], s1);
        s2 = fmaf(x2[(size_t)r*FDIM+k], f2W[(size_t)k*HIDN+h], s2);
    }
    o8[h] = lrelu(s1,0.01f)+lrelu(s2,0.01f);
    __syncthreads();
    if (h < 2){
        float s = clb[h];
        for (int k=0;k<HIDN;k++) s = fmaf(o8[k], clW[k*2+h], s);
        outp[16 + r*2 + h] = s;
    }
}

// ---------------------------------------------------------------------------
extern "C" void kernel_launch(void* const* d_in, const int* in_sizes, int n_in,
                              void* d_out, int out_size, void* d_ws, size_t ws_size,
                              hipStream_t stream) {
    (void)in_sizes; (void)n_in; (void)out_size; (void)ws_size;
    const float* x    = (const float*)d_in[0];
    const float* reh  = (const float*)d_in[1];
    const float* aW1  = (const float*)d_in[2];
    const float* ab1  = (const float*)d_in[3];
    const float* aW2  = (const float*)d_in[4];
    const float* cW   = (const float*)d_in[6];
    const float* cb   = (const float*)d_in[7];
    const float* dW1  = (const float*)d_in[8];
    const float* db1  = (const float*)d_in[9];
    const float* dW2  = (const float*)d_in[10];
    const float* db2  = (const float*)d_in[11];
    const float* g1W  = (const float*)d_in[12];
    const float* g1att= (const float*)d_in[13];
    const float* g1b  = (const float*)d_in[14];
    const float* n1w  = (const float*)d_in[15];
    const float* n1b  = (const float*)d_in[16];
    const float* n1s  = (const float*)d_in[17];
    const float* f1W  = (const float*)d_in[18];
    const float* f1b  = (const float*)d_in[19];
    const float* g2W  = (const float*)d_in[20];
    const float* g2att= (const float*)d_in[21];
    const float* g2b  = (const float*)d_in[22];
    const float* n2w  = (const float*)d_in[23];
    const float* n2b  = (const float*)d_in[24];
    const float* n2s  = (const float*)d_in[25];
    const float* f2W  = (const float*)d_in[26];
    const float* f2b  = (const float*)d_in[27];
    const float* clW  = (const float*)d_in[28];
    const float* clb  = (const float*)d_in[29];
    float* out = (float*)d_out;
    char* ws = (char*)d_ws;

    // workspace layout (bytes)
    float* scores = (float*)(ws + 0);              // 524288
    float* Mbuf   = (float*)(ws + 524288);         // 16384
    float* xc     = (float*)(ws + 540672);         // 16793600  (later reused as xs)
    float* xg1    = (float*)(ws + 17334272);       // 8396800
    float* xg     = (float*)(ws + 25731072);       // 16793600  (later reused as x2)
    float* rn     = (float*)(ws + 42524672);       // 32800
    int*   nbrp   = (int*)  (ws + 44656896);       // 131200
    float* eattr  = (float*)(ws + 44788224);       // 16793600
    int*   counts = (int*)  (ws + 61581824);       // 32800
    int*   csrOff = (int*)  (ws + 61614848);       // 32804
    int*   fillPos= (int*)  (ws + 61647872);       // 32800
    int*   csrE   = (int*)  (ws + 61680896);       // 131200
    float* w2     = (float*)(ws + 61812096);       // 2048
    float* ps     = (float*)(ws + 61814144);       // 32800
    float* pe     = (float*)(ws + 61847040);       // 32800
    float* alphan = (float*)(ws + 61880064);       // 131200
    float* out_e  = (float*)(ws + 62011264);       // 16793600
    float* out_n  = (float*)(ws + 78804864);       // 16793600
    float* part1  = (float*)(ws + 95598464);       // 131072
    float* part2  = (float*)(ws + 95729536);       // 131072
    float* mu     = (float*)(ws + 95860608);       // 2048
    float* gsc    = (float*)(ws + 95862656);       // 2048
    float* x1buf  = (float*)(ws + 95864704);       // 16793600
    float* scoresP= (float*)(ws + 112658304);      // 2097152
    float* xs     = xc;      // alias (xc dead after xg1 GEMM)
    float* x2buf  = xg;      // alias (xg dead after layer-1 xs GEMM)
    float* MP     = scoresP;
    unsigned short* gW1hi = (unsigned short*)scoresP;                   // 524288
    unsigned short* gW1lo = (unsigned short*)((char*)scoresP + 524288); // 524288
    unsigned short* gW2hi = (unsigned short*)((char*)scoresP + 1048576);// 524288
    unsigned short* gW2lo = (unsigned short*)((char*)scoresP + 1572864);// 524288
    unsigned short* WThi = (unsigned short*)eattr;               // 524288 B
    unsigned short* WTlo = (unsigned short*)((char*)eattr + 524288); // 524288 B
    unsigned short* xgh = (unsigned short*)out_e;            // 8396800 B
    int*   candI = (int*)((char*)out_e + 8396800);           // 4198400 B
    int*   htI   = (int*)((char*)out_e + 12595200);          // 262400 B
    float* candV = out_n;                                    // 4198400 B
    float* htV   = (float*)((char*)out_n + 4198400);         // 262400 B

    hipMemsetAsync(counts, 0, NNODE*sizeof(int), stream);
    hipMemsetAsync(fillPos, 0, NNODE*sizeof(int), stream);

    // ---- attention MIL pooling ----
    k_wsplit<<<1024,256,0,stream>>>(aW1, WThi, WTlo);
    k_scores<<<4096,256,0,stream>>>(x, WThi, WTlo, ab1, aW2, scoresP);
    k_scred<<<512,256,0,stream>>>(scoresP, scores);
    k_softmax<<<NBAGS,256,0,stream>>>(scores);
    k_M<<<dim3(MCHUNK,NBAGS),256,0,stream>>>(x, scores, MP);
    k_Mred<<<NBAGS,512,0,stream>>>(MP, Mbuf);
    k_logits_mlp<<<1,64,0,stream>>>(Mbuf, cW, cb, out);

    // conv-layer weight splits (scoresP region is dead after k_Mred)
    k_wsplit<<<1024,256,0,stream>>>(g1W, gW1hi, gW1lo);
    k_wsplit<<<1024,256,0,stream>>>(g2W, gW2hi, gW2lo);

    // ---- projector (fp32: keeps xg bit-exact for the exact kNN rescore) ----
    k_xc<<<(NNODE*FDIM+255)/256,256,0,stream>>>(Mbuf, reh, xc);
    k_gemm<<<dim3(2,(NNODE+63)/64),256,0,stream>>>(xc, dW1, db1, xg1, nullptr, NNODE, HIDN, FDIM, 0.01f);
    k_gemm<<<dim3(4,(NNODE+63)/64),256,0,stream>>>(xg1, dW2, db2, xg, xgh, NNODE, FDIM, HIDN, 0.01f);

    // ---- kNN graph: bf16 MFMA prefilter + exact fp32 rescore ----
    k_rowdot<<<NNODE,64,0,stream>>>(xg, nullptr, rn, FDIM, 1);
    k_simbf<<<dim3(BFSPLIT,(NNODE+63)/64),256,0,stream>>>(xgh, rn, candV, candI);
    k_rescore<<<dim3(NNODE/4,2),256,0,stream>>>(xg, rn, candV, candI, htV, htI);
    k_hmerge<<<(NNODE+255)/256,256,0,stream>>>(htV, htI, nbrp);
    k_eattr<<<NNODE,256,0,stream>>>(xg, nbrp, eattr);
    k_count<<<(NEDGE+255)/256,256,0,stream>>>(nbrp, counts);
    k_scan<<<1,256,0,stream>>>(counts, csrOff);
    k_fill<<<(NEDGE+255)/256,256,0,stream>>>(nbrp, csrOff, fillPos, csrE);

    // ---- two hypergraph conv layers (xs GEMM via bf16x3 MFMA) ----
    for (int layer=0; layer<2; ++layer){
        const float* Xin  = layer==0 ? xg   : x1buf;
        const float* W    = layer==0 ? g1W  : g2W;
        const unsigned short* Whi = layer==0 ? gW1hi : gW2hi;
        const unsigned short* Wlo = layer==0 ? gW1lo : gW2lo;
        const float* att  = layer==0 ? g1att: g2att;
        const float* gb   = layer==0 ? g1b  : g2b;
        const float* nw   = layer==0 ? n1w  : n2w;
        const float* nb_  = layer==0 ? n1b  : n2b;
        const float* ns   = layer==0 ? n1s  : n2s;
        float* Xout       = layer==0 ? x1buf: x2buf;

        k_gemm3<<<dim3(4,(NNODE+127)/128),256,0,stream>>>(Xin, Whi, Wlo, nullptr, xs, NNODE, FDIM, FDIM, 1.0f);
        k_watt<<<FDIM,64,0,stream>>>(W, att+FDIM, w2);
        k_rowdot<<<NNODE,64,0,stream>>>(xs, att, ps, FDIM, 0);
        k_rowdot<<<NNODE,64,0,stream>>>(eattr, w2, pe, FDIM, 0);
        k_alpha<<<(NEDGE+255)/256,256,0,stream>>>(nbrp, ps, pe, alphan);
        k_esm<<<(NNODE+255)/256,256,0,stream>>>(csrOff, csrE, alphan);
        k_oute<<<NNODE,256,0,stream>>>(xs, alphan, nbrp, out_e);
        k_outn<<<NNODE,256,0,stream>>>(out_e, alphan, csrOff, csrE, gb, out_n);
        k_colstat1<<<64,256,0,stream>>>(out_n, part1, part2);
        k_colstat2<<<2,256,0,stream>>>(part1, part2, nw, ns, mu, gsc);
        k_gnapply<<<(NNODE*FDIM+255)/256,256,0,stream>>>(out_n, mu, gsc, ns, nb_, Xout);
    }

    // ---- final heads (only rows 0..7 matter) ----
    k_final<<<NBAGS,HIDN,0,stream>>>(x1buf, x2buf, f1W, f1b, f2W, f2b, clW, clb, out);
}